// Round 3
// baseline (401.459 us; speedup 1.0000x reference)
//
#include <hip/hip_runtime.h>
#include <hip/hip_bf16.h>
#include <cstdint>
#include <cstddef>

#define N_  32
#define C_  64
#define T_  256
#define V_  25
#define R_  8
#define O_  64
#define K_  5
#define NU_ 17

// ---- k_main tiling ----
#define TT 16            // t per block
#define OT 16            // o per block (= one MFMA N-tile)
#define VP 28            // padded v slots per t: 28*2B = 56B, multiple of 8
#define ROWS (TT * VP)   // 448 LDS rows (t*VP+v)
#define MTILES (ROWS / 16)  // 28 MFMA M-tiles

#define OUT_ELEMS ((size_t)N_ * O_ * T_ * V_)   // 13,107,200

typedef __attribute__((ext_vector_type(8))) short bf16x8;
typedef __attribute__((ext_vector_type(4))) float f32x4;

static __device__ __forceinline__ unsigned short f2bf(float f) {
    union { float f; unsigned u; } c; c.f = f;
    unsigned r = (c.u + 0x7FFFu + ((c.u >> 16) & 1u)) >> 16;   // RTN-even
    return (unsigned short)r;
}
static __device__ __forceinline__ float bf_lo(unsigned d) {
    union { unsigned u; float f; } c; c.u = d << 16; return c.f;
}
static __device__ __forceinline__ float bf_hi(unsigned d) {
    union { unsigned u; float f; } c; c.u = d & 0xFFFF0000u; return c.f;
}

// ---------------------------------------------------------------------------
// Kernel 1: temporal mean pool  pool[n,c,v] = mean_t x[n,c,t,v]
// ---------------------------------------------------------------------------
__global__ void k_pool(const float* __restrict__ x, float* __restrict__ pool) {
    int nc = blockIdx.x;
    int t  = threadIdx.x;
    const float* px = x + ((size_t)nc * T_ + t) * V_;
    float acc[V_];
#pragma unroll
    for (int v = 0; v < V_; ++v) acc[v] = px[v];
#pragma unroll
    for (int off = 32; off > 0; off >>= 1) {
#pragma unroll
        for (int v = 0; v < V_; ++v) acc[v] += __shfl_down(acc[v], off, 64);
    }
    __shared__ float sm[4][V_];
    int wave = t >> 6, lane = t & 63;
    if (lane == 0) {
#pragma unroll
        for (int v = 0; v < V_; ++v) sm[wave][v] = acc[v];
    }
    __syncthreads();
    if (t < V_) {
        float s = sm[0][t] + sm[1][t] + sm[2][t] + sm[3][t];
        pool[(size_t)nc * V_ + t] = s * (1.0f / T_);
    }
}

// ---------------------------------------------------------------------------
// Kernel 2: t2 = b2 + W2·pool ;  tS = (v<17 ? b11+W11·pool : b12+W12·pool)
// ---------------------------------------------------------------------------
__global__ void k_tvals(const float* __restrict__ pool,
                        const float* __restrict__ W11, const float* __restrict__ b11,
                        const float* __restrict__ W12, const float* __restrict__ b12,
                        const float* __restrict__ W2,  const float* __restrict__ b2,
                        float* __restrict__ t2o, float* __restrict__ tSo) {
    int kn = blockIdx.x;
    int k = kn / N_, n = kn % N_;
    int tid = threadIdx.x;
    int r = tid >> 5, v = tid & 31;
    if (v >= V_) return;
    const float* pp = pool + (size_t)n * C_ * V_ + v;
    const float* w2 = W2 + ((size_t)k * R_ + r) * C_;
    const float* w1 = ((v < NU_) ? W11 : W12) + ((size_t)k * R_ + r) * C_;
    float a2 = b2[k * R_ + r];
    float a1 = (v < NU_) ? b11[k * R_ + r] : b12[k * R_ + r];
    for (int c = 0; c < C_; ++c) {
        float p = pp[(size_t)c * V_];
        a2 += w2[c] * p;
        a1 += w1[c] * p;
    }
    size_t idx = (((size_t)k * N_ + n) * R_ + r) * V_ + v;
    t2o[idx] = a2;
    tSo[idx] = a1;
}

// ---------------------------------------------------------------------------
// Kernel 3: graphs[k,n,o,u,v] = b4 + sum_r W4[k,o,r]*tanh(tS[ku,n,r,u]-t2[ku,n,r,v])
// ---------------------------------------------------------------------------
__global__ void k_graphs(const float* __restrict__ t2v, const float* __restrict__ tSv,
                         const float* __restrict__ W4, const float* __restrict__ b4,
                         float* __restrict__ graphs) {
    int kn = blockIdx.x;
    int k = kn / N_, n = kn % N_;
    int kup = (k + 1) % K_;
    __shared__ float F[R_][V_ * V_];
    __shared__ float w4s[O_][R_];
    __shared__ float b4s[O_];
    int tid = threadIdx.x;
    for (int i = tid; i < O_ * R_; i += 256) w4s[i / R_][i % R_] = W4[(size_t)k * O_ * R_ + i];
    if (tid < O_) b4s[tid] = b4[k * O_ + tid];
    for (int idx = tid; idx < R_ * V_ * V_; idx += 256) {
        int r = idx / (V_ * V_), uv = idx % (V_ * V_);
        int u = uv / V_, v = uv % V_;
        int ks = (u < NU_) ? kup : k;
        size_t base = (((size_t)ks * N_ + n) * R_ + r) * V_;
        F[r][uv] = tanhf(tSv[base + u] - t2v[base + v]);
    }
    __syncthreads();
    float* gout = graphs + ((size_t)k * N_ + n) * O_ * (V_ * V_);
    for (int idx = tid; idx < O_ * V_ * V_; idx += 256) {
        int o = idx / (V_ * V_), uv = idx % (V_ * V_);
        float a = b4s[o];
#pragma unroll
        for (int r = 0; r < R_; ++r) a += w4s[o][r] * F[r][uv];
        gout[idx] = a;
    }
}

// ---------------------------------------------------------------------------
// Kernel 4: hybrid MFMA (stage A) + VALU (stage B).
// Block = (n, 16 t's, 16 o's), 512 threads (8 waves).
//  Stage A (MFMA 16x16x32 bf16): X2[o][t*VP+v] = b3[k,o] + sum_c W3[k,o,c]*x[n,c,t,v]
//    A-frag: xT rows (m = t*VP+v), k = c ; B-frag: W3^T (k = c, n = o).
//    A lane map: m = l&15, c = (l>>4)*8+e ; B: o = l&15, c = (l>>4)*8+e.
//    C/D (m89-verified): col(o) = l&15, row(tv) = (l>>4)*4+reg -> 4 consecutive
//    rows => ds_write_b64 at X2[o][row], 8B-aligned (VP=28).
//  Stage B (VALU): thread = (o, t, u-half): acc[13] over k of
//    sum_v (graphs+A)[k,n,o,u,v] * X2_k[o][t][v].
// ---------------------------------------------------------------------------
__global__ __launch_bounds__(512, 1) void k_main(
    const float* __restrict__ x, const float* __restrict__ graphs,
    const float* __restrict__ Adj, const float* __restrict__ W3,
    const float* __restrict__ b3, float* __restrict__ out) {

    __shared__ unsigned short xT[ROWS * 64];   // bf16 bits, rows 128B, XOR-swizzled 16B slots
    __shared__ unsigned short X2[OT][ROWS];    // bf16 bits, [o][t*VP+v]
    __shared__ float Gs[OT][V_ * VP];          // fp32, [o][u*VP+v]

    const int tid = threadIdx.x;
    const int bid = blockIdx.x;
    const int ob = bid & 3;
    const int tb = (bid >> 2) & 15;
    const int n  = bid >> 6;
    const int obase = ob * OT;
    const int tbase = tb * TT;
    const int lane = tid & 63;
    const int wave = tid >> 6;

    // ---- one-time: stage x tile -> xT (transposed, bf16, swizzled) ----
    if (tid < ROWS) {
        const int row = tid;
        const int t = row / VP, v = row - t * VP;
        if (v < V_) {
            const float* gp = x + ((size_t)(n * C_) * T_ + (tbase + t)) * V_ + v;
#pragma unroll
            for (int cg = 0; cg < 8; ++cg) {
                unsigned short h[8];
#pragma unroll
                for (int j = 0; j < 8; ++j)
                    h[j] = f2bf(gp[(size_t)(cg * 8 + j) * (T_ * V_)]);
                uint4 pk;
                pk.x = (unsigned)h[0] | ((unsigned)h[1] << 16);
                pk.y = (unsigned)h[2] | ((unsigned)h[3] << 16);
                pk.z = (unsigned)h[4] | ((unsigned)h[5] << 16);
                pk.w = (unsigned)h[6] | ((unsigned)h[7] << 16);
                *(uint4*)((char*)xT + row * 128 + (((cg ^ (row & 7)) << 4))) = pk;
            }
        } else {
            // zero the pad rows (hygiene: keeps MFMA pad outputs finite)
            uint4 z; z.x = z.y = z.z = z.w = 0u;
#pragma unroll
            for (int cg = 0; cg < 8; ++cg)
                *(uint4*)((char*)xT + row * 128 + (((cg ^ (row & 7)) << 4))) = z;
        }
    }
    __syncthreads();

    // ---- stage-B thread mapping (fixed across k) ----
    const int so = tid >> 5;          // o-local 0..15
    const int st = (tid >> 1) & 15;   // t-local 0..15
    const int uh = tid & 1;           // u-half
    const int ubase = uh * 12;        // u = ubase + j, j=0..12 (u=12 duplicated, benign)

    float accB[13];
#pragma unroll
    for (int j = 0; j < 13; ++j) accB[j] = 0.0f;

    const int ol = lane & 15;         // stage-A o (B-frag n) / A-frag m offset
    const int eg = lane >> 4;         // k-element group

    for (int kb = 0; kb < K_; ++kb) {
        // ---- stage Gs_k = graphs + Adj (fp32, 28-padded rows) ----
        for (int i = tid; i < OT * 625; i += 512) {
            int o  = i / 625, uv = i - o * 625;
            int u  = uv / 25, v  = uv - u * 25;
            float g = graphs[(((size_t)kb * N_ + n) * O_ + obase + o) * 625 + uv]
                    + Adj[kb * 625 + uv];
            Gs[o][u * VP + v] = g;
        }

        // ---- stage A: MFMA into X2 ----
        bf16x8 wf0, wf1;
        {
            const float* wp0 = W3 + ((size_t)kb * O_ + obase + ol) * C_ + 0 * 32 + eg * 8;
            const float* wp1 = W3 + ((size_t)kb * O_ + obase + ol) * C_ + 1 * 32 + eg * 8;
#pragma unroll
            for (int e = 0; e < 8; ++e) {
                wf0[e] = (short)f2bf(wp0[e]);
                wf1[e] = (short)f2bf(wp1[e]);
            }
        }
        const float bias = b3[kb * O_ + obase + ol];

        for (int mt = wave; mt < MTILES; mt += 8) {
            const int rowb = mt * 16 + ol;
            f32x4 acc = {0.0f, 0.0f, 0.0f, 0.0f};
            {
                const bf16x8 a0 = *(const bf16x8*)((const char*)xT + rowb * 128 + (((eg + 0) ^ (rowb & 7)) << 4));
                acc = __builtin_amdgcn_mfma_f32_16x16x32_bf16(a0, wf0, acc, 0, 0, 0);
                const bf16x8 a1 = *(const bf16x8*)((const char*)xT + rowb * 128 + (((eg + 4) ^ (rowb & 7)) << 4));
                acc = __builtin_amdgcn_mfma_f32_16x16x32_bf16(a1, wf1, acc, 0, 0, 0);
            }
            const int r0 = mt * 16 + eg * 4;   // 4 consecutive tv rows, col = ol
            short4 pk;
            pk.x = (short)f2bf(acc[0] + bias);
            pk.y = (short)f2bf(acc[1] + bias);
            pk.z = (short)f2bf(acc[2] + bias);
            pk.w = (short)f2bf(acc[3] + bias);
            *(short4*)&X2[ol][r0] = pk;        // 8B-aligned (r0 % 4 == 0)
        }
        __syncthreads();

        // ---- stage B: VALU contraction ----
        {
            const unsigned int* xp = (const unsigned int*)&X2[so][st * VP];
            float xv[V_];
#pragma unroll
            for (int i = 0; i < 12; ++i) {
                unsigned d = xp[i];
                xv[2 * i]     = bf_lo(d);
                xv[2 * i + 1] = bf_hi(d);
            }
            xv[24] = bf_lo((unsigned)X2[so][st * VP + 24]);
#pragma unroll
            for (int j = 0; j < 13; ++j) {
                const float* g = &Gs[so][(ubase + j) * VP];
                float s = 0.0f;
#pragma unroll
                for (int v = 0; v < V_; ++v) s += g[v] * xv[v];
                accB[j] += s;
            }
        }
        __syncthreads();   // before next k's staging overwrites Gs / X2
    }

    // ---- out write ----
    float* po = out + (((size_t)n * O_ + obase + so) * T_ + tbase + st) * V_;
#pragma unroll
    for (int j = 0; j < 13; ++j) po[ubase + j] = accB[j];
}

// ---------------------------------------------------------------------------
extern "C" void kernel_launch(void* const* d_in, const int* in_sizes, int n_in,
                              void* d_out, int out_size, void* d_ws, size_t ws_size,
                              hipStream_t stream) {
    const float* x   = (const float*)d_in[0];
    const float* A   = (const float*)d_in[1];
    const float* W11 = (const float*)d_in[2];
    const float* b11 = (const float*)d_in[3];
    const float* W12 = (const float*)d_in[4];
    const float* b12 = (const float*)d_in[5];
    const float* W2  = (const float*)d_in[6];
    const float* b2  = (const float*)d_in[7];
    const float* W3  = (const float*)d_in[8];
    const float* b3  = (const float*)d_in[9];
    const float* W4  = (const float*)d_in[10];
    const float* b4  = (const float*)d_in[11];

    float* out    = (float*)d_out;
    float* graphs = out + OUT_ELEMS;   // second tuple element

    const size_t poolElems = (size_t)N_ * C_ * V_;
    const size_t tElems    = (size_t)K_ * N_ * R_ * V_;
    const size_t needBytes = (poolElems + 2 * tElems) * sizeof(float);
    float* scratch = (ws_size >= needBytes) ? (float*)d_ws : out;
    float* pool = scratch;
    float* t2v  = scratch + poolElems;
    float* tSv  = t2v + tElems;

    k_pool  <<<N_ * C_, 256, 0, stream>>>(x, pool);
    k_tvals <<<K_ * N_, 256, 0, stream>>>(pool, W11, b11, W12, b12, W2, b2, t2v, tSv);
    k_graphs<<<K_ * N_, 256, 0, stream>>>(t2v, tSv, W4, b4, graphs);
    k_main  <<<N_ * (T_ / TT) * (O_ / OT), 512, 0, stream>>>(x, graphs, A, W3, b3, out);
}

// Round 4
// 257.082 us; speedup vs baseline: 1.5616x; 1.5616x over previous
//
#include <hip/hip_runtime.h>
#include <cstdint>
#include <cstddef>

#define N_  32
#define C_  64
#define T_  256
#define V_  25
#define R_  8
#define O_  64
#define K_  5
#define NU_ 17
#define U_  25
#define CV  (C_ * V_)        // 1600
#define KC  64               // K-chunk (2 MFMA k-steps)
#define NCH (CV / KC)        // 25 chunks
#define OG  4                // o's per block (fast path)
#define NB  (OG * 32)        // 128 = N-dim of the GEMM

#define OUT_ELEMS ((size_t)N_ * O_ * T_ * V_)   // 13,107,200

typedef __attribute__((ext_vector_type(8))) short bf16x8;
typedef __attribute__((ext_vector_type(4))) float f32x4;

static __device__ __forceinline__ unsigned short f2bf(float f) {
    union { float f; unsigned u; } c; c.f = f;
    unsigned r = (c.u + 0x7FFFu + ((c.u >> 16) & 1u)) >> 16;   // RTN-even
    return (unsigned short)r;
}

// ---------------------------------------------------------------------------
// Kernel 1: temporal mean pool  pool[n,c,v] = mean_t x[n,c,t,v]
// ---------------------------------------------------------------------------
__global__ void k_pool(const float* __restrict__ x, float* __restrict__ pool) {
    int nc = blockIdx.x;
    int t  = threadIdx.x;
    const float* px = x + ((size_t)nc * T_ + t) * V_;
    float acc[V_];
#pragma unroll
    for (int v = 0; v < V_; ++v) acc[v] = px[v];
#pragma unroll
    for (int off = 32; off > 0; off >>= 1) {
#pragma unroll
        for (int v = 0; v < V_; ++v) acc[v] += __shfl_down(acc[v], off, 64);
    }
    __shared__ float sm[4][V_];
    int wave = t >> 6, lane = t & 63;
    if (lane == 0) {
#pragma unroll
        for (int v = 0; v < V_; ++v) sm[wave][v] = acc[v];
    }
    __syncthreads();
    if (t < V_) {
        float s = sm[0][t] + sm[1][t] + sm[2][t] + sm[3][t];
        pool[(size_t)nc * V_ + t] = s * (1.0f / T_);
    }
}

// ---------------------------------------------------------------------------
// Kernel 2: t2 = b2 + W2·pool ;  tS = (v<17 ? b11+W11·pool : b12+W12·pool)
// ---------------------------------------------------------------------------
__global__ void k_tvals(const float* __restrict__ pool,
                        const float* __restrict__ W11, const float* __restrict__ b11,
                        const float* __restrict__ W12, const float* __restrict__ b12,
                        const float* __restrict__ W2,  const float* __restrict__ b2,
                        float* __restrict__ t2o, float* __restrict__ tSo) {
    int kn = blockIdx.x;
    int k = kn / N_, n = kn % N_;
    int tid = threadIdx.x;
    int r = tid >> 5, v = tid & 31;
    if (v >= V_) return;
    const float* pp = pool + (size_t)n * C_ * V_ + v;
    const float* w2 = W2 + ((size_t)k * R_ + r) * C_;
    const float* w1 = ((v < NU_) ? W11 : W12) + ((size_t)k * R_ + r) * C_;
    float a2 = b2[k * R_ + r];
    float a1 = (v < NU_) ? b11[k * R_ + r] : b12[k * R_ + r];
    for (int c = 0; c < C_; ++c) {
        float p = pp[(size_t)c * V_];
        a2 += w2[c] * p;
        a1 += w1[c] * p;
    }
    size_t idx = (((size_t)k * N_ + n) * R_ + r) * V_ + v;
    t2o[idx] = a2;
    tSo[idx] = a1;
}

// ---------------------------------------------------------------------------
// Kernel 3: graphs[k,n,o,u,v] = b4 + sum_r W4[k,o,r]*tanh(tS[ku,n,r,u]-t2[ku,n,r,v])
// ---------------------------------------------------------------------------
__global__ void k_graphs(const float* __restrict__ t2v, const float* __restrict__ tSv,
                         const float* __restrict__ W4, const float* __restrict__ b4,
                         float* __restrict__ graphs) {
    int kn = blockIdx.x;
    int k = kn / N_, n = kn % N_;
    int kup = (k + 1) % K_;
    __shared__ float F[R_][V_ * V_];
    __shared__ float w4s[O_][R_];
    __shared__ float b4s[O_];
    int tid = threadIdx.x;
    for (int i = tid; i < O_ * R_; i += 256) w4s[i / R_][i % R_] = W4[(size_t)k * O_ * R_ + i];
    if (tid < O_) b4s[tid] = b4[k * O_ + tid];
    for (int idx = tid; idx < R_ * V_ * V_; idx += 256) {
        int r = idx / (V_ * V_), uv = idx % (V_ * V_);
        int u = uv / V_, v = uv % V_;
        int ks = (u < NU_) ? kup : k;
        size_t base = (((size_t)ks * N_ + n) * R_ + r) * V_;
        F[r][uv] = tanhf(tSv[base + u] - t2v[base + v]);
    }
    __syncthreads();
    float* gout = graphs + ((size_t)k * N_ + n) * O_ * (V_ * V_);
    for (int idx = tid; idx < O_ * V_ * V_; idx += 256) {
        int o = idx / (V_ * V_), uv = idx % (V_ * V_);
        float a = b4s[o];
#pragma unroll
        for (int r = 0; r < R_; ++r) a += w4s[o][r] * F[r][uv];
        gout[idx] = a;
    }
}

// ---------------------------------------------------------------------------
// Kernel: x transpose+cast  xT[n][t][c*25+v] (bf16)  from x[n][c][t][v] (fp32)
// ---------------------------------------------------------------------------
__global__ void k_xcast(const float* __restrict__ x, unsigned short* __restrict__ xT) {
    __shared__ unsigned short tile[16][CV + 8];   // +8 us pad: row stride 3216 B
    int bid = blockIdx.x;
    int n = bid >> 4, tb = bid & 15;
    int tid = threadIdx.x;
    for (int i = tid; i < C_ * 16 * V_; i += 256) {
        int c = i / 400, r = i - c * 400;
        int t = r / 25, v = r - t * 25;
        float val = x[(((size_t)n * C_ + c) * T_ + tb * 16 + t) * V_ + v];
        tile[t][c * 25 + v] = f2bf(val);
    }
    __syncthreads();
    unsigned* dst = (unsigned*)(xT + (size_t)n * T_ * CV + (size_t)tb * 16 * CV);
    for (int i = tid; i < 16 * (CV / 2); i += 256) {
        int t = i / 800, j = i - t * 800;
        dst[t * 800 + j] = *(const unsigned*)&tile[t][2 * j];
    }
}

// ---------------------------------------------------------------------------
// Kernel: bias[n,o,u] = sum_k b3[k,o] * sum_v (graphs[k,n,o,u,v] + A[k,u,v])
// ---------------------------------------------------------------------------
__global__ void k_bias(const float* __restrict__ graphs, const float* __restrict__ Adj,
                       const float* __restrict__ b3, float* __restrict__ bias) {
    int bid = blockIdx.x;             // n = bid>>3, og = bid&7
    int n = bid >> 3, og = bid & 7;
    int ol = threadIdx.x >> 5, u = threadIdx.x & 31;
    int o = og * 8 + ol;
    if (u >= U_) return;
    float s = 0.f;
    for (int k = 0; k < K_; ++k) {
        const float* gp = graphs + (((size_t)k * N_ + n) * O_ + o) * 625 + u * 25;
        const float* ap = Adj + k * 625 + u * 25;
        float t = 0.f;
#pragma unroll
        for (int v = 0; v < V_; ++v) t += gp[v] + ap[v];
        s += t * b3[k * O_ + o];
    }
    bias[((size_t)n * O_ + o) * U_ + u] = s;
}

// ---------------------------------------------------------------------------
// Kernel 4 FAST: one GEMM per (n, 4-o group):
//   out[t, (o,u)] = bias + sum_cv xT[t][cv] * H[cv][(o,u)]
//   H[cv][(o,u)] = sum_k W3[k,o,c] * (graphs+A)[k,n,o,u,v]   (formed in LDS)
// 512 thr (8 waves, 2 wm x 4 wn), M=256, N=128, K=1600, KC=64, double-buffered.
// All LDS tiles use slot-XOR swizzle (slot ^ (row&7)) for even bank spread.
// ---------------------------------------------------------------------------
__global__ __launch_bounds__(512, 2) void k_main_fast(
    const unsigned short* __restrict__ xT,   // [N][T][CV] bf16 bits
    const float* __restrict__ graphs,        // [K][N][O][625]
    const float* __restrict__ Adj,           // [K][625]
    const float* __restrict__ W3,            // [K][O][C]
    const float* __restrict__ bias,          // [N][O][25]
    float* __restrict__ out) {

    __shared__ unsigned short Ab[2][256 * KC];   // 2 x 32 KB
    __shared__ unsigned short Hs[2][NB * KC];    // 2 x 16 KB
    __shared__ float Gls[OG * 625 * K_];         // 50 KB  [(o*625+uv)*5 + k]
    __shared__ float W3s[OG * C_ * K_];          // 5 KB   [(o*64+c)*5 + k]

    const int tid = threadIdx.x;
    const int bid = blockIdx.x;
    const int obase = (bid & 15) * OG;
    const int n = bid >> 4;

    // ---- stage Gls (graphs + Adj, fp32) and W3s ----
    for (int i = tid; i < OG * 625 * K_; i += 512) {
        int k  = i / (OG * 625);
        int r  = i - k * (OG * 625);
        int o  = r / 625;
        int uv = r - o * 625;
        float g = graphs[(((size_t)k * N_ + n) * O_ + obase + o) * 625 + uv]
                + Adj[k * 625 + uv];
        Gls[(o * 625 + uv) * K_ + k] = g;
    }
    for (int i = tid; i < OG * C_ * K_; i += 512) {
        int o = i / (C_ * K_);
        int r = i - o * (C_ * K_);
        int c = r / K_;
        int k = r - c * K_;
        W3s[i] = W3[((size_t)k * O_ + obase + o) * C_ + c];
    }

    const size_t xTn = (size_t)n * T_ * CV;   // ushort offset

    uint4 av[4];
#define A_LOAD(kc) { \
    _Pragma("unroll") for (int i2 = 0; i2 < 4; ++i2) { \
        int L = i2 * 512 + tid; int t = L >> 3, s = L & 7; \
        av[i2] = *(const uint4*)(xT + xTn + (size_t)t * CV + (kc) * KC + s * 8); } }
#define A_WRITE(buf) { \
    _Pragma("unroll") for (int i2 = 0; i2 < 4; ++i2) { \
        int L = i2 * 512 + tid; int t = L >> 3, s = L & 7; \
        *(uint4*)((char*)&Ab[buf][0] + t * 128 + ((s ^ (t & 7)) << 4)) = av[i2]; } }

    // H-forming thread mapping: (o, u, j-quarter)
    const int fo = tid >> 7;           // 0..3
    const int fu = (tid >> 2) & 31;    // 0..31
    const int fq = tid & 3;            // 0..3
#define H_FORM(buf, kc) { \
    int nrow = fo * 32 + fu; \
    char* hbase = (char*)&Hs[buf][0] + nrow * 128; \
    if (fu >= U_) { \
        _Pragma("unroll") for (int jj = 0; jj < 16; ++jj) { int j = fq * 16 + jj; \
            *(unsigned short*)(hbase + (((j >> 3) ^ (nrow & 7)) << 4) + ((j & 7) << 1)) = 0; } \
    } else { \
        _Pragma("unroll") for (int jj = 0; jj < 16; ++jj) { int j = fq * 16 + jj; \
            int cv = (kc) * KC + j; \
            int c = (cv * 5243) >> 17; int v = cv - c * 25; \
            const float* gp = &Gls[(fo * 625 + fu * 25 + v) * K_]; \
            const float* wp = &W3s[(fo * C_ + c) * K_]; \
            float h = gp[0]*wp[0] + gp[1]*wp[1] + gp[2]*wp[2] + gp[3]*wp[3] + gp[4]*wp[4]; \
            *(unsigned short*)(hbase + (((j >> 3) ^ (nrow & 7)) << 4) + ((j & 7) << 1)) = f2bf(h); } \
    } }

    const int lane = tid & 63;
    const int wv = tid >> 6;          // 0..7
    const int wm = wv >> 2;           // 0..1  (t-base wm*128)
    const int wn = wv & 3;            // 0..3  (n-base wn*32)
    const int lr = lane & 15;
    const int eg = lane >> 4;

    f32x4 acc[8][2];
#pragma unroll
    for (int mt = 0; mt < 8; ++mt)
#pragma unroll
        for (int nt = 0; nt < 2; ++nt) acc[mt][nt] = (f32x4){0.f, 0.f, 0.f, 0.f};

    // ---- prologue: chunk 0 ----
    A_LOAD(0); A_WRITE(0);
    __syncthreads();           // Gls/W3s ready
    H_FORM(0, 0);
    __syncthreads();           // Hs[0], Ab[0] ready

    for (int kc = 0; kc < NCH; ++kc) {
        const int cur = kc & 1;
        if (kc + 1 < NCH) A_LOAD(kc + 1);      // issue early (hide HBM/L2 latency)
#pragma unroll
        for (int ks = 0; ks < 2; ++ks) {
            const char* hb = (const char*)&Hs[cur][0];
            const int slot = (ks << 2) | eg;
            const int n0 = wn * 32 + lr;
            const int n1 = wn * 32 + 16 + lr;
            bf16x8 b0 = *(const bf16x8*)(hb + n0 * 128 + ((slot ^ (n0 & 7)) << 4));
            bf16x8 b1 = *(const bf16x8*)(hb + n1 * 128 + ((slot ^ (n1 & 7)) << 4));
            const char* ab = (const char*)&Ab[cur][0];
#pragma unroll
            for (int mt = 0; mt < 8; ++mt) {
                int t = wm * 128 + mt * 16 + lr;
                bf16x8 a = *(const bf16x8*)(ab + t * 128 + ((slot ^ (t & 7)) << 4));
                acc[mt][0] = __builtin_amdgcn_mfma_f32_16x16x32_bf16(a, b0, acc[mt][0], 0, 0, 0);
                acc[mt][1] = __builtin_amdgcn_mfma_f32_16x16x32_bf16(a, b1, acc[mt][1], 0, 0, 0);
            }
        }
        if (kc + 1 < NCH) { A_WRITE((kc + 1) & 1); H_FORM((kc + 1) & 1, kc + 1); }
        __syncthreads();
    }

    // ---- epilogue: C/D layout col = lane&15, row = eg*4 + r ----
#pragma unroll
    for (int nt = 0; nt < 2; ++nt) {
        int ncol = wn * 32 + nt * 16 + lr;
        int ol = ncol >> 5;
        int u  = ncol & 31;
        if (u < U_) {
            const size_t obg = (size_t)n * O_ + obase + ol;
            float bv = bias[obg * U_ + u];
            float* ob = out + obg * T_ * V_ + u;
#pragma unroll
            for (int mt = 0; mt < 8; ++mt) {
                int t0 = wm * 128 + mt * 16 + eg * 4;
#pragma unroll
                for (int r2 = 0; r2 < 4; ++r2)
                    ob[(size_t)(t0 + r2) * V_] = acc[mt][nt][r2] + bv;
            }
        }
    }
#undef A_LOAD
#undef A_WRITE
#undef H_FORM
}

// ---------------------------------------------------------------------------
// Kernel 4 SLOW (fallback, proven R2 path; bounds relaxed to kill spills)
// ---------------------------------------------------------------------------
#define OB 4
#define TB 64
__global__ __launch_bounds__(256, 1) void k_main_slow(
    const float* __restrict__ x, const float* __restrict__ graphs,
    const float* __restrict__ A, const float* __restrict__ W3,
    const float* __restrict__ b3, float* __restrict__ out) {
    int bid = blockIdx.x;
    int tb = bid & 3;
    int ob = (bid >> 2) & 15;
    int n  = bid >> 6;
    int tid = threadIdx.x;
    int ol = tid >> 6;
    int tl = tid & 63;
    int t = tb * TB + tl;
    int o = ob * OB + ol;

    __shared__ float Gs[K_][OB][V_][28];
    __shared__ float W3s[K_][OB][C_];
    __shared__ float b3s[K_][OB];

    for (int i = tid; i < K_ * OB * V_ * V_; i += 256) {
        int k   = i / (OB * V_ * V_);
        int rem = i % (OB * V_ * V_);
        int oo  = rem / (V_ * V_);
        int uv  = rem % (V_ * V_);
        Gs[k][oo][uv / V_][uv % V_] =
            graphs[(((size_t)k * N_ + n) * O_ + ob * OB + oo) * (V_ * V_) + uv]
            + A[k * V_ * V_ + uv];
    }
    for (int i = tid; i < K_ * OB * C_; i += 256) {
        int k   = i / (OB * C_);
        int rem = i % (OB * C_);
        int oo  = rem / C_, c = rem % C_;
        W3s[k][oo][c] = W3[((size_t)k * O_ + ob * OB + oo) * C_ + c];
    }
    if (tid < K_ * OB) b3s[tid / OB][tid % OB] = b3[(tid / OB) * O_ + ob * OB + tid % OB];
    __syncthreads();

    float x2[K_][V_];
#pragma unroll
    for (int k = 0; k < K_; ++k)
#pragma unroll
        for (int v = 0; v < V_; ++v) x2[k][v] = b3s[k][ol];

    const float* xb = x + ((size_t)n * C_ * T_ + t) * V_;
    for (int c = 0; c < C_; ++c) {
        const float* p = xb + (size_t)c * T_ * V_;
        float xv[V_];
#pragma unroll
        for (int v = 0; v < V_; ++v) xv[v] = p[v];
#pragma unroll
        for (int k = 0; k < K_; ++k) {
            float w = W3s[k][ol][c];
#pragma unroll
            for (int v = 0; v < V_; ++v) x2[k][v] += w * xv[v];
        }
    }

    float acc[V_];
#pragma unroll
    for (int u = 0; u < V_; ++u) acc[u] = 0.0f;
#pragma unroll
    for (int k = 0; k < K_; ++k) {
#pragma unroll
        for (int u = 0; u < V_; ++u) {
            const float* gr = &Gs[k][ol][u][0];
            float s = 0.0f;
#pragma unroll
            for (int v = 0; v < V_; ++v) s += gr[v] * x2[k][v];
            acc[u] += s;
        }
    }
    float* po = out + (((size_t)n * O_ + o) * T_ + t) * V_;
#pragma unroll
    for (int u = 0; u < V_; ++u) po[u] = acc[u];
}

// ---------------------------------------------------------------------------
extern "C" void kernel_launch(void* const* d_in, const int* in_sizes, int n_in,
                              void* d_out, int out_size, void* d_ws, size_t ws_size,
                              hipStream_t stream) {
    const float* x   = (const float*)d_in[0];
    const float* A   = (const float*)d_in[1];
    const float* W11 = (const float*)d_in[2];
    const float* b11 = (const float*)d_in[3];
    const float* W12 = (const float*)d_in[4];
    const float* b12 = (const float*)d_in[5];
    const float* W2  = (const float*)d_in[6];
    const float* b2  = (const float*)d_in[7];
    const float* W3  = (const float*)d_in[8];
    const float* b3  = (const float*)d_in[9];
    const float* W4  = (const float*)d_in[10];
    const float* b4  = (const float*)d_in[11];

    float* out    = (float*)d_out;
    float* graphs = out + OUT_ELEMS;   // second tuple element

    const size_t xT_bytes = sizeof(unsigned short) * (size_t)N_ * T_ * CV;  // 26.2 MB
    const size_t fastReq  = (size_t)(1 << 20) + xT_bytes;
    const bool fast = (ws_size >= fastReq);

    const size_t poolElems = (size_t)N_ * C_ * V_;      // 51,200
    const size_t tElems    = (size_t)K_ * N_ * R_ * V_; // 32,000
    const size_t slowNeed  = (poolElems + 2 * tElems) * sizeof(float);

    float* scratch = (fast || ws_size >= slowNeed + 51200 * 4) ? (float*)d_ws : out;
    float* pool  = scratch;
    float* t2v   = scratch + poolElems;
    float* tSv   = t2v + tElems;
    float* biasb = tSv + tElems;                         // 51,200 floats
    unsigned short* xT = (unsigned short*)((char*)d_ws + (1 << 20));

    k_pool  <<<N_ * C_, 256, 0, stream>>>(x, pool);
    k_tvals <<<K_ * N_, 256, 0, stream>>>(pool, W11, b11, W12, b12, W2, b2, t2v, tSv);
    k_graphs<<<K_ * N_, 256, 0, stream>>>(t2v, tSv, W4, b4, graphs);

    if (fast) {
        k_xcast<<<N_ * 16, 256, 0, stream>>>(x, xT);
        k_bias <<<N_ * 8, 256, 0, stream>>>(graphs, A, b3, biasb);
        k_main_fast<<<N_ * 16, 512, 0, stream>>>(xT, graphs, A, W3, biasb, out);
    } else {
        k_main_slow<<<N_ * (O_ / OB) * (T_ / TB), 256, 0, stream>>>(x, graphs, A, W3, b3, out);
    }
}

// Round 5
// 186.399 us; speedup vs baseline: 2.1538x; 1.3792x over previous
//
#include <hip/hip_runtime.h>
#include <cstdint>
#include <cstddef>

#define N_  32
#define C_  64
#define T_  256
#define V_  25
#define R_  8
#define O_  64
#define K_  5
#define NU_ 17
#define U_  25
#define CV  (C_ * V_)        // 1600
#define KC  64               // K-chunk (2 MFMA k-steps)
#define NCH (CV / KC)        // 25 chunks
#define OG  4                // o's per block (fast path)
#define NB  (OG * 32)        // 128 = N-dim of the GEMM

#define OUT_ELEMS ((size_t)N_ * O_ * T_ * V_)   // 13,107,200

typedef __attribute__((ext_vector_type(8))) short bf16x8;
typedef __attribute__((ext_vector_type(4))) float f32x4;

static __device__ __forceinline__ unsigned short f2bf(float f) {
    union { float f; unsigned u; } c; c.f = f;
    unsigned r = (c.u + 0x7FFFu + ((c.u >> 16) & 1u)) >> 16;   // RTN-even
    return (unsigned short)r;
}
static __device__ __forceinline__ float bf2f(unsigned short h) {
    union { unsigned u; float f; } c; c.u = ((unsigned)h) << 16; return c.f;
}

// ---------------------------------------------------------------------------
// k_xcast: xT[n][t][c*25+v] (bf16) from x[n][c][t][v] (fp32), PLUS per-tb
// partial pooling sums pp[n][tb][c*25+v] (fp32, sum over the block's 16 t's).
// ---------------------------------------------------------------------------
__global__ void k_xcast(const float* __restrict__ x, unsigned short* __restrict__ xT,
                        float* __restrict__ pp) {
    __shared__ unsigned short tile[16][CV + 8];   // row stride 3216 B
    int bid = blockIdx.x;
    int n = bid >> 4, tb = bid & 15;
    int tid = threadIdx.x;
    for (int i = tid; i < C_ * 16 * V_; i += 256) {
        int c = i / 400, r = i - c * 400;
        int t = r / 25, v = r - t * 25;
        float val = x[(((size_t)n * C_ + c) * T_ + tb * 16 + t) * V_ + v];
        tile[t][c * 25 + v] = f2bf(val);
    }
    __syncthreads();
    unsigned* dst = (unsigned*)(xT + (size_t)n * T_ * CV + (size_t)tb * 16 * CV);
    for (int i = tid; i < 16 * (CV / 2); i += 256) {
        int t = i / 800, j = i - t * 800;
        dst[t * 800 + j] = *(const unsigned*)&tile[t][2 * j];
    }
    // partial pool: sum over this block's 16 t's (from bf16 tile; err ~1e-4)
    float* ppd = pp + ((size_t)n * 16 + tb) * CV;
    for (int e = tid; e < CV; e += 256) {
        float s = 0.f;
#pragma unroll
        for (int t = 0; t < 16; ++t) s += bf2f(tile[t][e]);
        ppd[e] = s;
    }
}

// pool[n][cv] = (1/T) * sum_tb pp[n][tb][cv]
__global__ void k_poolsum(const float* __restrict__ pp, float* __restrict__ pool) {
    int idx = blockIdx.x * 256 + threadIdx.x;   // < N_*CV = 51200
    int n = idx / CV, cv = idx - n * CV;
    float s = 0.f;
#pragma unroll
    for (int tb = 0; tb < 16; ++tb) s += pp[((size_t)n * 16 + tb) * CV + cv];
    pool[idx] = s * (1.0f / T_);
}

// classic pool (tier-2 fallback when pp doesn't fit ws)
__global__ void k_pool(const float* __restrict__ x, float* __restrict__ pool) {
    int nc = blockIdx.x;
    int t  = threadIdx.x;
    const float* px = x + ((size_t)nc * T_ + t) * V_;
    float acc[V_];
#pragma unroll
    for (int v = 0; v < V_; ++v) acc[v] = px[v];
#pragma unroll
    for (int off = 32; off > 0; off >>= 1) {
#pragma unroll
        for (int v = 0; v < V_; ++v) acc[v] += __shfl_down(acc[v], off, 64);
    }
    __shared__ float sm[4][V_];
    int wave = t >> 6, lane = t & 63;
    if (lane == 0) {
#pragma unroll
        for (int v = 0; v < V_; ++v) sm[wave][v] = acc[v];
    }
    __syncthreads();
    if (t < V_) {
        float s = sm[0][t] + sm[1][t] + sm[2][t] + sm[3][t];
        pool[(size_t)nc * V_ + t] = s * (1.0f / T_);
    }
}

// ---------------------------------------------------------------------------
// k_tvals: t2 = b2 + W2·pool ;  tS = (v<17 ? b11+W11·pool : b12+W12·pool)
// ---------------------------------------------------------------------------
__global__ void k_tvals(const float* __restrict__ pool,
                        const float* __restrict__ W11, const float* __restrict__ b11,
                        const float* __restrict__ W12, const float* __restrict__ b12,
                        const float* __restrict__ W2,  const float* __restrict__ b2,
                        float* __restrict__ t2o, float* __restrict__ tSo) {
    int kn = blockIdx.x;
    int k = kn / N_, n = kn % N_;
    int tid = threadIdx.x;
    int r = tid >> 5, v = tid & 31;
    if (v >= V_) return;
    const float* pp = pool + (size_t)n * C_ * V_ + v;
    const float* w2 = W2 + ((size_t)k * R_ + r) * C_;
    const float* w1 = ((v < NU_) ? W11 : W12) + ((size_t)k * R_ + r) * C_;
    float a2 = b2[k * R_ + r];
    float a1 = (v < NU_) ? b11[k * R_ + r] : b12[k * R_ + r];
    for (int c = 0; c < C_; ++c) {
        float p = pp[(size_t)c * V_];
        a2 += w2[c] * p;
        a1 += w1[c] * p;
    }
    size_t idx = (((size_t)k * N_ + n) * R_ + r) * V_ + v;
    t2o[idx] = a2;
    tSo[idx] = a1;
}

// ---------------------------------------------------------------------------
// k_graphs: graphs[k,n,o,u,v] = b4 + sum_r W4[k,o,r]*tanh(tS[ku,n,r,u]-t2[ku,n,r,v])
// ---------------------------------------------------------------------------
__global__ void k_graphs(const float* __restrict__ t2v, const float* __restrict__ tSv,
                         const float* __restrict__ W4, const float* __restrict__ b4,
                         float* __restrict__ graphs) {
    int kn = blockIdx.x;
    int k = kn / N_, n = kn % N_;
    int kup = (k + 1) % K_;
    __shared__ float F[R_][V_ * V_];
    __shared__ float w4s[O_][R_];
    __shared__ float b4s[O_];
    int tid = threadIdx.x;
    for (int i = tid; i < O_ * R_; i += 256) w4s[i / R_][i % R_] = W4[(size_t)k * O_ * R_ + i];
    if (tid < O_) b4s[tid] = b4[k * O_ + tid];
    for (int idx = tid; idx < R_ * V_ * V_; idx += 256) {
        int r = idx / (V_ * V_), uv = idx % (V_ * V_);
        int u = uv / V_, v = uv % V_;
        int ks = (u < NU_) ? kup : k;
        size_t base = (((size_t)ks * N_ + n) * R_ + r) * V_;
        F[r][uv] = tanhf(tSv[base + u] - t2v[base + v]);
    }
    __syncthreads();
    float* gout = graphs + ((size_t)k * N_ + n) * O_ * (V_ * V_);
    for (int idx = tid; idx < O_ * V_ * V_; idx += 256) {
        int o = idx / (V_ * V_), uv = idx % (V_ * V_);
        float a = b4s[o];
#pragma unroll
        for (int r = 0; r < R_; ++r) a += w4s[o][r] * F[r][uv];
        gout[idx] = a;
    }
}

// ---------------------------------------------------------------------------
// k_bias: bias[n,o,u] = sum_k b3[k,o] * sum_v (graphs[k,n,o,u,v] + A[k,u,v])
// ---------------------------------------------------------------------------
__global__ void k_bias(const float* __restrict__ graphs, const float* __restrict__ Adj,
                       const float* __restrict__ b3, float* __restrict__ bias) {
    int bid = blockIdx.x;
    int n = bid >> 3, og = bid & 7;
    int ol = threadIdx.x >> 5, u = threadIdx.x & 31;
    int o = og * 8 + ol;
    if (u >= U_) return;
    float s = 0.f;
    for (int k = 0; k < K_; ++k) {
        const float* gp = graphs + (((size_t)k * N_ + n) * O_ + o) * 625 + u * 25;
        const float* ap = Adj + k * 625 + u * 25;
        float t = 0.f;
#pragma unroll
        for (int v = 0; v < V_; ++v) t += gp[v] + ap[v];
        s += t * b3[k * O_ + o];
    }
    bias[((size_t)n * O_ + o) * U_ + u] = s;
}

// ---------------------------------------------------------------------------
// k_main_fast: per (n, 4-o group) GEMM  out[t,(o,u)] = bias + A·H
//   A[t][cv] = xT (bf16), H[cv][(o,u)] = sum_k W3[k,o,c]*(graphs+Adj)[k,n,o,u,v]
// 512 thr, waves 4(wm)x2(wn); M=256, N=128, K=1600, KC=64, double-buffered.
// H formed in LDS: thread=(j->(c,v) fixed; wave->16-row block -> o,u-range),
// W3 k-vector in regs, Gls as float4(k0..3)+float(k4) -> aligned b128+b32.
// ---------------------------------------------------------------------------
__global__ __launch_bounds__(512, 2) void k_main_fast(
    const unsigned short* __restrict__ xT,   // [N][T][CV] bf16 bits
    const float* __restrict__ graphs,        // [K][N][O][625]
    const float* __restrict__ Adj,           // [K][625]
    const float* __restrict__ W3,            // [K][O][C]
    const float* __restrict__ bias,          // [N][O][25]
    float* __restrict__ out) {

    __shared__ unsigned short Ab[2][256 * KC];   // 64 KB, row=t (128B), slot-XOR
    __shared__ unsigned short Hs[2][NB * KC];    // 32 KB, row=ncol (128B), slot-XOR
    __shared__ f32x4 Gls4[OG * 625];             // 40 KB, idx=(o*25+v)*25+u -> k0..3
    __shared__ float Gls1[OG * 625];             // 10 KB, k4
    __shared__ f32x4 W3s4[C_ * OG];              //  4 KB, idx=c*OG+o -> k0..3
    __shared__ float W3s1[C_ * OG];              //  1 KB

    const int tid = threadIdx.x;
    const int bid = blockIdx.x;
    const int obase = (bid & 15) * OG;
    const int n = bid >> 4;

    // ---- stage Gls (graphs + Adj) ----
    for (int i = tid; i < OG * 625; i += 512) {
        int o  = i / 625, uv = i - o * 625;
        int u  = uv / 25, v  = uv - u * 25;
        size_t gb = ((size_t)n * O_ + obase + o) * 625 + uv;
        const size_t ks = (size_t)N_ * O_ * 625;
        f32x4 g4;
        g4[0] = graphs[gb + 0 * ks] + Adj[0 * 625 + uv];
        g4[1] = graphs[gb + 1 * ks] + Adj[1 * 625 + uv];
        g4[2] = graphs[gb + 2 * ks] + Adj[2 * 625 + uv];
        g4[3] = graphs[gb + 3 * ks] + Adj[3 * 625 + uv];
        int idx = (o * 25 + v) * 25 + u;
        Gls4[idx] = g4;
        Gls1[idx] = graphs[gb + 4 * ks] + Adj[4 * 625 + uv];
    }
    // ---- stage W3s ----
    if (tid < C_ * OG) {
        int c = tid >> 2, o = tid & 3;
        size_t wb = ((size_t)obase + o) * C_ + c;
        const size_t ks = (size_t)O_ * C_;
        f32x4 w;
        w[0] = W3[wb + 0 * ks]; w[1] = W3[wb + 1 * ks];
        w[2] = W3[wb + 2 * ks]; w[3] = W3[wb + 3 * ks];
        W3s4[tid] = w;
        W3s1[tid] = W3[wb + 4 * ks];
    }

    const size_t xTn = (size_t)n * T_ * CV;

    uint4 av[4];
#define A_LOAD(kc) { \
    _Pragma("unroll") for (int i2 = 0; i2 < 4; ++i2) { \
        int L = i2 * 512 + tid; int t = L >> 3, s = L & 7; \
        av[i2] = *(const uint4*)(xT + xTn + (size_t)t * CV + (kc) * KC + s * 8); } }
#define A_WRITE(buf) { \
    _Pragma("unroll") for (int i2 = 0; i2 < 4; ++i2) { \
        int L = i2 * 512 + tid; int t = L >> 3, s = L & 7; \
        *(uint4*)((char*)&Ab[buf][0] + t * 128 + ((s ^ (t & 7)) << 4)) = av[i2]; } }

    // H_FORM thread mapping: j = lane (cv), wave rb -> rows rb*16..rb*16+15
    const int lane = tid & 63;
    const int rb = tid >> 6;            // 0..7
    const int fo = rb >> 1;             // o-local (fixed per thread)
    const int fub = (rb & 1) * 16;      // u-base
#define H_FORM(buf, kc) { \
    int cv = (kc) * KC + lane; \
    int c = (cv * 5243) >> 17; int v = cv - c * 25; \
    f32x4 wv = W3s4[c * OG + fo]; float w1 = W3s1[c * OG + fo]; \
    int idx0 = (fo * 25 + v) * 25 + fub; \
    char* hb = (char*)&Hs[buf][0] + ((lane >> 3) << 4) + ((lane & 7) << 1); \
    _Pragma("unroll") for (int i2 = 0; i2 < 16; ++i2) { \
        float h = 0.f; \
        if (fub + i2 < U_) { \
            f32x4 g = Gls4[idx0 + i2]; float g1 = Gls1[idx0 + i2]; \
            h = wv[0]*g[0] + wv[1]*g[1] + wv[2]*g[2] + wv[3]*g[3] + w1*g1; } \
        int row = rb * 16 + i2; \
        *(unsigned short*)(hb + row * 128 + (((row & 7) << 4) ^ 0)) = f2bf(h); } }
    // NOTE: XOR slot with row: slot' = (lane>>3) ^ (row&7). Implemented by
    // XORing the 16B-slot bits of the base; rewritten explicitly below.
#undef H_FORM
#define H_FORM(buf, kc) { \
    int cv = (kc) * KC + lane; \
    int c = (cv * 5243) >> 17; int v = cv - c * 25; \
    f32x4 wv = W3s4[c * OG + fo]; float w1 = W3s1[c * OG + fo]; \
    int idx0 = (fo * 25 + v) * 25 + fub; \
    _Pragma("unroll") for (int i2 = 0; i2 < 16; ++i2) { \
        float h = 0.f; \
        if (fub + i2 < U_) { \
            f32x4 g = Gls4[idx0 + i2]; float g1 = Gls1[idx0 + i2]; \
            h = wv[0]*g[0] + wv[1]*g[1] + wv[2]*g[2] + wv[3]*g[3] + w1*g1; } \
        int row = rb * 16 + i2; \
        int off = row * 128 + ((((lane >> 3) ^ (row & 7)) << 4)) + ((lane & 7) << 1); \
        *(unsigned short*)((char*)&Hs[buf][0] + off) = f2bf(h); } }

    // MFMA wave grid: 4 (wm) x 2 (wn); per wave 4 mt x 4 nt tiles
    const int wv_ = tid >> 6;
    const int wm = wv_ >> 1;            // 0..3 -> t-base wm*64
    const int wn = wv_ & 1;             // 0..1 -> ncol-base wn*64
    const int lr = lane & 15;
    const int eg = lane >> 4;

    f32x4 acc[4][4];
#pragma unroll
    for (int mt = 0; mt < 4; ++mt)
#pragma unroll
        for (int nt = 0; nt < 4; ++nt) acc[mt][nt] = (f32x4){0.f, 0.f, 0.f, 0.f};

    // ---- prologue ----
    A_LOAD(0); A_WRITE(0);
    __syncthreads();           // Gls/W3s (and Ab[0]) visible
    H_FORM(0, 0);
    __syncthreads();           // Hs[0] visible

    for (int kc = 0; kc < NCH; ++kc) {
        const int cur = kc & 1;
        if (kc + 1 < NCH) A_LOAD(kc + 1);
        __builtin_amdgcn_s_setprio(1);
#pragma unroll
        for (int ks = 0; ks < 2; ++ks) {
            const int slot = (ks << 2) | eg;
            const char* hbp = (const char*)&Hs[cur][0];
            bf16x8 b[4];
#pragma unroll
            for (int nt = 0; nt < 4; ++nt) {
                int nc = wn * 64 + nt * 16 + lr;
                b[nt] = *(const bf16x8*)(hbp + nc * 128 + ((slot ^ (nc & 7)) << 4));
            }
            const char* abp = (const char*)&Ab[cur][0];
#pragma unroll
            for (int mt = 0; mt < 4; ++mt) {
                int t = wm * 64 + mt * 16 + lr;
                bf16x8 a = *(const bf16x8*)(abp + t * 128 + ((slot ^ (t & 7)) << 4));
#pragma unroll
                for (int nt = 0; nt < 4; ++nt)
                    acc[mt][nt] = __builtin_amdgcn_mfma_f32_16x16x32_bf16(a, b[nt], acc[mt][nt], 0, 0, 0);
            }
        }
        __builtin_amdgcn_s_setprio(0);
        if (kc + 1 < NCH) { A_WRITE((kc + 1) & 1); H_FORM((kc + 1) & 1, kc + 1); }
        __syncthreads();
    }

    // ---- epilogue ----
#pragma unroll
    for (int nt = 0; nt < 4; ++nt) {
        int ncol = wn * 64 + nt * 16 + lr;
        int ol = ncol >> 5;
        int u  = ncol & 31;
        if (u < U_) {
            const size_t obg = (size_t)n * O_ + obase + ol;
            float bv = bias[obg * U_ + u];
            float* ob = out + obg * T_ * V_ + u;
#pragma unroll
            for (int mt = 0; mt < 4; ++mt) {
                int t0 = wm * 64 + mt * 16 + eg * 4;
#pragma unroll
                for (int r2 = 0; r2 < 4; ++r2)
                    ob[(size_t)(t0 + r2) * V_] = acc[mt][nt][r2] + bv;
            }
        }
    }
#undef A_LOAD
#undef A_WRITE
#undef H_FORM
}

// ---------------------------------------------------------------------------
// k_main_slow (fallback, proven R2 path)
// ---------------------------------------------------------------------------
#define OB 4
#define TB 64
__global__ __launch_bounds__(256, 1) void k_main_slow(
    const float* __restrict__ x, const float* __restrict__ graphs,
    const float* __restrict__ A, const float* __restrict__ W3,
    const float* __restrict__ b3, float* __restrict__ out) {
    int bid = blockIdx.x;
    int tb = bid & 3;
    int ob = (bid >> 2) & 15;
    int n  = bid >> 6;
    int tid = threadIdx.x;
    int ol = tid >> 6;
    int tl = tid & 63;
    int t = tb * TB + tl;
    int o = ob * OB + ol;

    __shared__ float Gs[K_][OB][V_][28];
    __shared__ float W3s[K_][OB][C_];
    __shared__ float b3s[K_][OB];

    for (int i = tid; i < K_ * OB * V_ * V_; i += 256) {
        int k   = i / (OB * V_ * V_);
        int rem = i % (OB * V_ * V_);
        int oo  = rem / (V_ * V_);
        int uv  = rem % (V_ * V_);
        Gs[k][oo][uv / V_][uv % V_] =
            graphs[(((size_t)k * N_ + n) * O_ + ob * OB + oo) * (V_ * V_) + uv]
            + A[k * V_ * V_ + uv];
    }
    for (int i = tid; i < K_ * OB * C_; i += 256) {
        int k   = i / (OB * C_);
        int rem = i % (OB * C_);
        int oo  = rem / C_, c = rem % C_;
        W3s[k][oo][c] = W3[((size_t)k * O_ + ob * OB + oo) * C_ + c];
    }
    if (tid < K_ * OB) b3s[tid / OB][tid % OB] = b3[(tid / OB) * O_ + ob * OB + tid % OB];
    __syncthreads();

    float x2[K_][V_];
#pragma unroll
    for (int k = 0; k < K_; ++k)
#pragma unroll
        for (int v = 0; v < V_; ++v) x2[k][v] = b3s[k][ol];

    const float* xb = x + ((size_t)n * C_ * T_ + t) * V_;
    for (int c = 0; c < C_; ++c) {
        const float* p = xb + (size_t)c * T_ * V_;
        float xv[V_];
#pragma unroll
        for (int v = 0; v < V_; ++v) xv[v] = p[v];
#pragma unroll
        for (int k = 0; k < K_; ++k) {
            float w = W3s[k][ol][c];
#pragma unroll
            for (int v = 0; v < V_; ++v) x2[k][v] += w * xv[v];
        }
    }

    float acc[V_];
#pragma unroll
    for (int u = 0; u < V_; ++u) acc[u] = 0.0f;
#pragma unroll
    for (int k = 0; k < K_; ++k) {
#pragma unroll
        for (int u = 0; u < V_; ++u) {
            const float* gr = &Gs[k][ol][u][0];
            float s = 0.0f;
#pragma unroll
            for (int v = 0; v < V_; ++v) s += gr[v] * x2[k][v];
            acc[u] += s;
        }
    }
    float* po = out + (((size_t)n * O_ + o) * T_ + t) * V_;
#pragma unroll
    for (int u = 0; u < V_; ++u) po[u] = acc[u];
}

// ---------------------------------------------------------------------------
extern "C" void kernel_launch(void* const* d_in, const int* in_sizes, int n_in,
                              void* d_out, int out_size, void* d_ws, size_t ws_size,
                              hipStream_t stream) {
    const float* x   = (const float*)d_in[0];
    const float* A   = (const float*)d_in[1];
    const float* W11 = (const float*)d_in[2];
    const float* b11 = (const float*)d_in[3];
    const float* W12 = (const float*)d_in[4];
    const float* b12 = (const float*)d_in[5];
    const float* W2  = (const float*)d_in[6];
    const float* b2  = (const float*)d_in[7];
    const float* W3  = (const float*)d_in[8];
    const float* b3  = (const float*)d_in[9];
    const float* W4  = (const float*)d_in[10];
    const float* b4  = (const float*)d_in[11];

    float* out    = (float*)d_out;
    float* graphs = out + OUT_ELEMS;   // second tuple element

    const size_t xT_bytes = sizeof(unsigned short) * (size_t)N_ * T_ * CV;  // 26.2 MB
    const size_t pp_bytes = sizeof(float) * (size_t)N_ * 16 * CV;           //  3.3 MB
    const size_t hdr      = (size_t)(1 << 20);
    const bool fast  = (ws_size >= hdr + xT_bytes);             // tier >= 2
    const bool fused = (ws_size >= hdr + xT_bytes + pp_bytes);  // tier 1

    const size_t poolElems = (size_t)N_ * C_ * V_;      // 51,200
    const size_t tElems    = (size_t)K_ * N_ * R_ * V_; // 32,000
    const size_t slowNeed  = (poolElems + 2 * tElems + poolElems) * sizeof(float);

    float* scratch = (fast || ws_size >= slowNeed) ? (float*)d_ws : out;
    float* pool  = scratch;
    float* t2v   = scratch + poolElems;
    float* tSv   = t2v + tElems;
    float* biasb = tSv + tElems;
    unsigned short* xT = (unsigned short*)((char*)d_ws + hdr);
    float* pp = (float*)((char*)d_ws + hdr + xT_bytes);

    if (fused) {
        k_xcast  <<<N_ * 16, 256, 0, stream>>>(x, xT, pp);
        k_poolsum<<<(N_ * CV) / 256, 256, 0, stream>>>(pp, pool);
    } else {
        k_pool<<<N_ * C_, 256, 0, stream>>>(x, pool);
        if (fast) {
            // still need xT for the fast main kernel (pp path unavailable)
            k_xcast<<<N_ * 16, 256, 0, stream>>>(x, xT, pool /*dummy, overwritten below*/);
            k_pool <<<N_ * C_, 256, 0, stream>>>(x, pool);   // re-derive pool correctly
        }
    }
    k_tvals <<<K_ * N_, 256, 0, stream>>>(pool, W11, b11, W12, b12, W2, b2, t2v, tSv);
    k_graphs<<<K_ * N_, 256, 0, stream>>>(t2v, tSv, W4, b4, graphs);

    if (fast) {
        k_bias<<<N_ * 8, 256, 0, stream>>>(graphs, A, b3, biasb);
        k_main_fast<<<N_ * 16, 512, 0, stream>>>(xT, graphs, A, W3, biasb, out);
    } else {
        k_main_slow<<<N_ * (O_ / OB) * (TB == 64 ? 4 : 4), 256, 0, stream>>>(x, graphs, A, W3, b3, out);
    }
}

// Round 6
// 181.837 us; speedup vs baseline: 2.2078x; 1.0251x over previous
//
#include <hip/hip_runtime.h>
#include <cstdint>
#include <cstddef>

#define N_  32
#define C_  64
#define T_  256
#define V_  25
#define R_  8
#define O_  64
#define K_  5
#define NU_ 17
#define U_  25
#define CV  (C_ * V_)        // 1600
#define KC  32               // K-chunk = 1 MFMA k-step
#define NCH (CV / KC)        // 50 chunks
#define OG  4                // o's per block
#define NB  (OG * 32)        // 128 ncols

#define OUT_ELEMS ((size_t)N_ * O_ * T_ * V_)   // 13,107,200

typedef __attribute__((ext_vector_type(8))) short bf16x8;
typedef __attribute__((ext_vector_type(4))) float f32x4;

static __device__ __forceinline__ unsigned short f2bf(float f) {
    union { float f; unsigned u; } c; c.f = f;
    unsigned r = (c.u + 0x7FFFu + ((c.u >> 16) & 1u)) >> 16;   // RTN-even
    return (unsigned short)r;
}
static __device__ __forceinline__ float bf2f(unsigned short h) {
    union { unsigned u; float f; } c; c.u = ((unsigned)h) << 16; return c.f;
}

// ---------------------------------------------------------------------------
// k_xcast: fragment-native xT3[n][tt(16)][s(200)][tl(16)][ke(8)] (bf16) from
// x[n][c][t][v] (fp32); element (t,cv): tt=t>>4, tl=t&15, s=cv>>3, ke=cv&7.
// Also emits per-t-block partial pool sums pp[n][tb][cv].
// ---------------------------------------------------------------------------
__global__ void k_xcast(const float* __restrict__ x, unsigned short* __restrict__ xT3,
                        float* __restrict__ pp) {
    __shared__ unsigned short tile[16][CV + 8];   // row stride 3216 B
    int bid = blockIdx.x;
    int n = bid >> 4, tb = bid & 15;
    int tid = threadIdx.x;
    for (int i = tid; i < C_ * 16 * V_; i += 256) {
        int c = i / 400, r = i - c * 400;
        int t = r / 25, v = r - t * 25;
        float val = x[(((size_t)n * C_ + c) * T_ + tb * 16 + t) * V_ + v];
        tile[t][c * 25 + v] = f2bf(val);
    }
    __syncthreads();
    // write fragment tiles: dst = ((n*16+tb)*200 + s)*128 + tl*8
    unsigned short* dstb = xT3 + ((size_t)(n * 16 + tb) * 200) * 128;
    for (int i = tid; i < 200 * 16; i += 256) {
        int s = i >> 4, tl = i & 15;
        uint4 v4 = *(const uint4*)&tile[tl][s * 8];
        *(uint4*)(dstb + (size_t)s * 128 + tl * 8) = v4;
    }
    // partial pool
    float* ppd = pp + ((size_t)n * 16 + tb) * CV;
    for (int e = tid; e < CV; e += 256) {
        float s = 0.f;
#pragma unroll
        for (int t = 0; t < 16; ++t) s += bf2f(tile[t][e]);
        ppd[e] = s;
    }
}

// pool[n][cv] = (1/T) * sum_tb pp[n][tb][cv]
__global__ void k_poolsum(const float* __restrict__ pp, float* __restrict__ pool) {
    int idx = blockIdx.x * 256 + threadIdx.x;   // < N_*CV
    int n = idx / CV, cv = idx - n * CV;
    float s = 0.f;
#pragma unroll
    for (int tb = 0; tb < 16; ++tb) s += pp[((size_t)n * 16 + tb) * CV + cv];
    pool[idx] = s * (1.0f / T_);
}

// classic pool (slow tier)
__global__ void k_pool(const float* __restrict__ x, float* __restrict__ pool) {
    int nc = blockIdx.x;
    int t  = threadIdx.x;
    const float* px = x + ((size_t)nc * T_ + t) * V_;
    float acc[V_];
#pragma unroll
    for (int v = 0; v < V_; ++v) acc[v] = px[v];
#pragma unroll
    for (int off = 32; off > 0; off >>= 1) {
#pragma unroll
        for (int v = 0; v < V_; ++v) acc[v] += __shfl_down(acc[v], off, 64);
    }
    __shared__ float sm[4][V_];
    int wave = t >> 6, lane = t & 63;
    if (lane == 0) {
#pragma unroll
        for (int v = 0; v < V_; ++v) sm[wave][v] = acc[v];
    }
    __syncthreads();
    if (t < V_) {
        float s = sm[0][t] + sm[1][t] + sm[2][t] + sm[3][t];
        pool[(size_t)nc * V_ + t] = s * (1.0f / T_);
    }
}

// ---------------------------------------------------------------------------
// k_tvals: t2 = b2 + W2·pool ;  tS = (v<17 ? b11+W11·pool : b12+W12·pool)
// ---------------------------------------------------------------------------
__global__ void k_tvals(const float* __restrict__ pool,
                        const float* __restrict__ W11, const float* __restrict__ b11,
                        const float* __restrict__ W12, const float* __restrict__ b12,
                        const float* __restrict__ W2,  const float* __restrict__ b2,
                        float* __restrict__ t2o, float* __restrict__ tSo) {
    int kn = blockIdx.x;
    int k = kn / N_, n = kn % N_;
    int tid = threadIdx.x;
    int r = tid >> 5, v = tid & 31;
    if (v >= V_) return;
    const float* pp = pool + (size_t)n * C_ * V_ + v;
    const float* w2 = W2 + ((size_t)k * R_ + r) * C_;
    const float* w1 = ((v < NU_) ? W11 : W12) + ((size_t)k * R_ + r) * C_;
    float a2 = b2[k * R_ + r];
    float a1 = (v < NU_) ? b11[k * R_ + r] : b12[k * R_ + r];
    for (int c = 0; c < C_; ++c) {
        float p = pp[(size_t)c * V_];
        a2 += w2[c] * p;
        a1 += w1[c] * p;
    }
    size_t idx = (((size_t)k * N_ + n) * R_ + r) * V_ + v;
    t2o[idx] = a2;
    tSo[idx] = a1;
}

// ---------------------------------------------------------------------------
// k_graphs: graphs[k,n,o,u,v] = b4 + sum_r W4[k,o,r]*tanh(tS[ku,n,r,u]-t2[ku,n,r,v])
// ---------------------------------------------------------------------------
__global__ void k_graphs(const float* __restrict__ t2v, const float* __restrict__ tSv,
                         const float* __restrict__ W4, const float* __restrict__ b4,
                         float* __restrict__ graphs) {
    int kn = blockIdx.x;
    int k = kn / N_, n = kn % N_;
    int kup = (k + 1) % K_;
    __shared__ float F[R_][V_ * V_];
    __shared__ float w4s[O_][R_];
    __shared__ float b4s[O_];
    int tid = threadIdx.x;
    for (int i = tid; i < O_ * R_; i += 256) w4s[i / R_][i % R_] = W4[(size_t)k * O_ * R_ + i];
    if (tid < O_) b4s[tid] = b4[k * O_ + tid];
    for (int idx = tid; idx < R_ * V_ * V_; idx += 256) {
        int r = idx / (V_ * V_), uv = idx % (V_ * V_);
        int u = uv / V_, v = uv % V_;
        int ks = (u < NU_) ? kup : k;
        size_t base = (((size_t)ks * N_ + n) * R_ + r) * V_;
        F[r][uv] = tanhf(tSv[base + u] - t2v[base + v]);
    }
    __syncthreads();
    float* gout = graphs + ((size_t)k * N_ + n) * O_ * (V_ * V_);
    for (int idx = tid; idx < O_ * V_ * V_; idx += 256) {
        int o = idx / (V_ * V_), uv = idx % (V_ * V_);
        float a = b4s[o];
#pragma unroll
        for (int r = 0; r < R_; ++r) a += w4s[o][r] * F[r][uv];
        gout[idx] = a;
    }
}

// ---------------------------------------------------------------------------
// k_main_fast: per (n, 4-o group) GEMM  out[t,ncol] = bias + A·H
//   A[t][cv] = xT3 fragments (global, never staged in LDS)
//   H[cv][ncol] formed per K-chunk in k-major LDS: Hs[slot(4)][ncol(128)][8k]
//   Gls: f32x4(k0..3) + bf16(k4) at idx = o*625 + v*25 + u  (u lane-consec)
// 512 thr (8 waves, wm 0..3 x wn 0..1), M=256 N=128 K=1600, KC=32, dbuf Hs,
// ONE barrier per chunk. bias computed in-block from staged Gls.
// ---------------------------------------------------------------------------
__global__ __launch_bounds__(512, 4) void k_main_fast(
    const unsigned short* __restrict__ xT3,  // [N][16][200][16][8] bf16 bits
    const float* __restrict__ graphs,        // [K][N][O][625]
    const float* __restrict__ Adj,           // [K][625]
    const float* __restrict__ W3,            // [K][O][C]
    const float* __restrict__ b3,            // [K][O]
    float* __restrict__ out) {

    __shared__ unsigned short Hs[2][4][NB][8];   // 16 KB
    __shared__ f32x4 Gls4[OG * 625];             // 40 KB (k0..3)
    __shared__ unsigned short Gk4[OG * 625];     //  5 KB (k4, bf16)
    __shared__ f32x4 W3s4[C_ * OG];              //  4 KB (k0..3)
    __shared__ float W3k4[C_ * OG];              //  1 KB (k4)
    __shared__ float biasS[NB];                  // 512 B

    const int tid = threadIdx.x;
    const int bid = blockIdx.x;
    const int obase = (bid & 15) * OG;
    const int n = bid >> 4;
    const int lane = tid & 63;
    const int wv_ = tid >> 6;

    // ---- stage Gls (graphs + Adj) at idx = o*625 + v*25 + u ----
    const size_t kstride = (size_t)N_ * O_ * 625;
    for (int i = tid; i < OG * 625; i += 512) {
        int o = i / 625, uv = i - o * 625;
        int u = uv / 25, v = uv - u * 25;
        size_t gb = ((size_t)n * O_ + obase + o) * 625 + uv;
        f32x4 g4;
        g4[0] = graphs[gb]               + Adj[uv];
        g4[1] = graphs[gb + kstride]     + Adj[625 + uv];
        g4[2] = graphs[gb + 2 * kstride] + Adj[1250 + uv];
        g4[3] = graphs[gb + 3 * kstride] + Adj[1875 + uv];
        float g5 = graphs[gb + 4 * kstride] + Adj[2500 + uv];
        int idx = o * 625 + v * 25 + u;
        Gls4[idx] = g4;
        Gk4[idx] = f2bf(g5);
    }
    // ---- stage W3 (idx = c*OG + o) ----
    if (tid < C_ * OG) {
        int c = tid >> 2, o = tid & 3;
        size_t wb = ((size_t)obase + o) * C_ + c;
        const size_t wstr = (size_t)O_ * C_;
        f32x4 w;
        w[0] = W3[wb]; w[1] = W3[wb + wstr]; w[2] = W3[wb + 2 * wstr]; w[3] = W3[wb + 3 * wstr];
        W3s4[tid] = w;
        W3k4[tid] = W3[wb + 4 * wstr];
    }
    __syncthreads();

    // ---- in-block bias: biasS[ncol] = sum_k b3[k,o] * sum_v G[k][o][u][v] ----
    if (tid < NB) {
        int o = tid >> 5, u = tid & 31;
        float bv = 0.f;
        if (u < U_) {
            f32x4 s4 = {0.f, 0.f, 0.f, 0.f};
            float s5 = 0.f;
            for (int v = 0; v < V_; ++v) {
                int idx = o * 625 + v * 25 + u;
                f32x4 g = Gls4[idx];
                s4 += g;
                s5 += bf2f(Gk4[idx]);
            }
            bv = s4[0] * b3[0 * O_ + obase + o] + s4[1] * b3[1 * O_ + obase + o]
               + s4[2] * b3[2 * O_ + obase + o] + s4[3] * b3[3 * O_ + obase + o]
               + s5 * b3[4 * O_ + obase + o];
        }
        biasS[tid] = bv;
    }

    // ---- H_FORM: wave -> (slot = wv&3, half = wv>>2); thread owns 1 ncol x 8 cv ----
    const int sl = wv_ & 3;
    const int hncol = (wv_ >> 2) * 64 + lane;
    const int ho = hncol >> 5;
    const int hu = hncol & 31;
    auto h_form = [&](int buf, int kc) {
        unsigned hp[4];
#pragma unroll
        for (int j2 = 0; j2 < 4; ++j2) {
            float h0 = 0.f, h1 = 0.f;
            if (hu < U_) {
                {
                    int cv = kc * KC + sl * 8 + 2 * j2;
                    int c = (cv * 5243) >> 17; int v = cv - c * 25;
                    int gi = ho * 625 + v * 25 + hu;
                    f32x4 g = Gls4[gi]; f32x4 w = W3s4[c * OG + ho];
                    h0 = g[0]*w[0] + g[1]*w[1] + g[2]*w[2] + g[3]*w[3]
                       + bf2f(Gk4[gi]) * W3k4[c * OG + ho];
                }
                {
                    int cv = kc * KC + sl * 8 + 2 * j2 + 1;
                    int c = (cv * 5243) >> 17; int v = cv - c * 25;
                    int gi = ho * 625 + v * 25 + hu;
                    f32x4 g = Gls4[gi]; f32x4 w = W3s4[c * OG + ho];
                    h1 = g[0]*w[0] + g[1]*w[1] + g[2]*w[2] + g[3]*w[3]
                       + bf2f(Gk4[gi]) * W3k4[c * OG + ho];
                }
            }
            hp[j2] = (unsigned)f2bf(h0) | ((unsigned)f2bf(h1) << 16);
        }
        uint4 hv; hv.x = hp[0]; hv.y = hp[1]; hv.z = hp[2]; hv.w = hp[3];
        *(uint4*)&Hs[buf][sl][hncol][0] = hv;
    };

    // ---- MFMA wave grid ----
    const int wm = wv_ >> 1;            // 0..3 -> t-base wm*64
    const int wn = wv_ & 1;             // 0..1 -> ncol-base wn*64
    const int lr = lane & 15;
    const int eg = lane >> 4;

    f32x4 acc[4][4];
#pragma unroll
    for (int mt = 0; mt < 4; ++mt)
#pragma unroll
        for (int nt = 0; nt < 4; ++nt) acc[mt][nt] = (f32x4){0.f, 0.f, 0.f, 0.f};

    h_form(0, 0);
    __syncthreads();

    const unsigned short* An = xT3 + (size_t)n * (T_ * CV);

    for (int kc = 0; kc < NCH; ++kc) {
        const int cur = kc & 1;
        // A-fragments straight from global (coalesced 1KB per instr, L1/L2-hot)
        uint4 av[4];
#pragma unroll
        for (int mt = 0; mt < 4; ++mt) {
            int tt = wm * 4 + mt;
            av[mt] = *(const uint4*)(An + ((size_t)(tt * 200 + kc * 4 + eg)) * 128 + lr * 8);
        }
        bf16x8 b[4];
#pragma unroll
        for (int nt = 0; nt < 4; ++nt)
            b[nt] = *(const bf16x8*)&Hs[cur][eg][wn * 64 + nt * 16 + lr][0];
        __builtin_amdgcn_s_setprio(1);
#pragma unroll
        for (int mt = 0; mt < 4; ++mt) {
            bf16x8 a;
            { union { uint4 u; bf16x8 h; } cvt; cvt.u = av[mt]; a = cvt.h; }
#pragma unroll
            for (int nt = 0; nt < 4; ++nt)
                acc[mt][nt] = __builtin_amdgcn_mfma_f32_16x16x32_bf16(a, b[nt], acc[mt][nt], 0, 0, 0);
        }
        __builtin_amdgcn_s_setprio(0);
        if (kc + 1 < NCH) h_form(cur ^ 1, kc + 1);
        __syncthreads();
    }

    // ---- epilogue: C/D col = lane&15 (ncol), row = eg*4 + r (t) ----
#pragma unroll
    for (int nt = 0; nt < 4; ++nt) {
        int ncol = wn * 64 + nt * 16 + lr;
        int ol = ncol >> 5;
        int u  = ncol & 31;
        if (u < U_) {
            float bv = biasS[ncol];
            float* ob = out + ((size_t)n * O_ + obase + ol) * T_ * V_ + u;
#pragma unroll
            for (int mt = 0; mt < 4; ++mt) {
                int t0 = wm * 64 + mt * 16 + eg * 4;
#pragma unroll
                for (int r2 = 0; r2 < 4; ++r2)
                    ob[(size_t)(t0 + r2) * V_] = acc[mt][nt][r2] + bv;
            }
        }
    }
}

// ---------------------------------------------------------------------------
// k_main_slow (fallback, proven R2 path)
// ---------------------------------------------------------------------------
#define OB 4
#define TB 64
__global__ __launch_bounds__(256, 1) void k_main_slow(
    const float* __restrict__ x, const float* __restrict__ graphs,
    const float* __restrict__ A, const float* __restrict__ W3,
    const float* __restrict__ b3, float* __restrict__ out) {
    int bid = blockIdx.x;
    int tb = bid & 3;
    int ob = (bid >> 2) & 15;
    int n  = bid >> 6;
    int tid = threadIdx.x;
    int ol = tid >> 6;
    int tl = tid & 63;
    int t = tb * TB + tl;
    int o = ob * OB + ol;

    __shared__ float Gs[K_][OB][V_][28];
    __shared__ float W3s[K_][OB][C_];
    __shared__ float b3s[K_][OB];

    for (int i = tid; i < K_ * OB * V_ * V_; i += 256) {
        int k   = i / (OB * V_ * V_);
        int rem = i % (OB * V_ * V_);
        int oo  = rem / (V_ * V_);
        int uv  = rem % (V_ * V_);
        Gs[k][oo][uv / V_][uv % V_] =
            graphs[(((size_t)k * N_ + n) * O_ + ob * OB + oo) * (V_ * V_) + uv]
            + A[k * V_ * V_ + uv];
    }
    for (int i = tid; i < K_ * OB * C_; i += 256) {
        int k   = i / (OB * C_);
        int rem = i % (OB * C_);
        int oo  = rem / C_, c = rem % C_;
        W3s[k][oo][c] = W3[((size_t)k * O_ + ob * OB + oo) * C_ + c];
    }
    if (tid < K_ * OB) b3s[tid / OB][tid % OB] = b3[(tid / OB) * O_ + ob * OB + tid % OB];
    __syncthreads();

    float x2[K_][V_];
#pragma unroll
    for (int k = 0; k < K_; ++k)
#pragma unroll
        for (int v = 0; v < V_; ++v) x2[k][v] = b3s[k][ol];

    const float* xb = x + ((size_t)n * C_ * T_ + t) * V_;
    for (int c = 0; c < C_; ++c) {
        const float* p = xb + (size_t)c * T_ * V_;
        float xv[V_];
#pragma unroll
        for (int v = 0; v < V_; ++v) xv[v] = p[v];
#pragma unroll
        for (int k = 0; k < K_; ++k) {
            float w = W3s[k][ol][c];
#pragma unroll
            for (int v = 0; v < V_; ++v) x2[k][v] += w * xv[v];
        }
    }

    float acc[V_];
#pragma unroll
    for (int u = 0; u < V_; ++u) acc[u] = 0.0f;
#pragma unroll
    for (int k = 0; k < K_; ++k) {
#pragma unroll
        for (int u = 0; u < V_; ++u) {
            const float* gr = &Gs[k][ol][u][0];
            float s = 0.0f;
#pragma unroll
            for (int v = 0; v < V_; ++v) s += gr[v] * x2[k][v];
            acc[u] += s;
        }
    }
    float* po = out + (((size_t)n * O_ + o) * T_ + t) * V_;
#pragma unroll
    for (int u = 0; u < V_; ++u) po[u] = acc[u];
}

// ---------------------------------------------------------------------------
extern "C" void kernel_launch(void* const* d_in, const int* in_sizes, int n_in,
                              void* d_out, int out_size, void* d_ws, size_t ws_size,
                              hipStream_t stream) {
    const float* x   = (const float*)d_in[0];
    const float* A   = (const float*)d_in[1];
    const float* W11 = (const float*)d_in[2];
    const float* b11 = (const float*)d_in[3];
    const float* W12 = (const float*)d_in[4];
    const float* b12 = (const float*)d_in[5];
    const float* W2  = (const float*)d_in[6];
    const float* b2  = (const float*)d_in[7];
    const float* W3  = (const float*)d_in[8];
    const float* b3  = (const float*)d_in[9];
    const float* W4  = (const float*)d_in[10];
    const float* b4  = (const float*)d_in[11];

    float* out    = (float*)d_out;
    float* graphs = out + OUT_ELEMS;   // second tuple element

    const size_t xT_bytes = sizeof(unsigned short) * (size_t)N_ * T_ * CV;  // 26.2 MB
    const size_t pp_bytes = sizeof(float) * (size_t)N_ * 16 * CV;           //  3.3 MB
    const size_t hdr      = (size_t)(1 << 20);
    const bool fast = (ws_size >= hdr + xT_bytes + pp_bytes);

    const size_t poolElems = (size_t)N_ * C_ * V_;      // 51,200
    const size_t tElems    = (size_t)K_ * N_ * R_ * V_; // 32,000
    const size_t slowNeed  = (poolElems + 2 * tElems) * sizeof(float);

    float* scratch = (fast || ws_size >= slowNeed) ? (float*)d_ws : out;
    float* pool = scratch;
    float* t2v  = scratch + poolElems;
    float* tSv  = t2v + tElems;
    unsigned short* xT3 = (unsigned short*)((char*)d_ws + hdr);
    float* pp = (float*)((char*)d_ws + hdr + xT_bytes);

    if (fast) {
        k_xcast  <<<N_ * 16, 256, 0, stream>>>(x, xT3, pp);
        k_poolsum<<<(N_ * CV) / 256, 256, 0, stream>>>(pp, pool);
    } else {
        k_pool<<<N_ * C_, 256, 0, stream>>>(x, pool);
    }
    k_tvals <<<K_ * N_, 256, 0, stream>>>(pool, W11, b11, W12, b12, W2, b2, t2v, tSv);
    k_graphs<<<K_ * N_, 256, 0, stream>>>(t2v, tSv, W4, b4, graphs);

    if (fast) {
        k_main_fast<<<N_ * 16, 512, 0, stream>>>(xT3, graphs, A, W3, b3, out);
    } else {
        k_main_slow<<<N_ * (O_ / OB) * 4, 256, 0, stream>>>(x, graphs, A, W3, b3, out);
    }
}

// Round 7
// 139.848 us; speedup vs baseline: 2.8707x; 1.3003x over previous
//
#include <hip/hip_runtime.h>
#include <cstdint>
#include <cstddef>

#define N_  32
#define C_  64
#define T_  256
#define V_  25
#define R_  8
#define O_  64
#define K_  5
#define NU_ 17
#define U_  25
#define CV  (C_ * V_)        // 1600
#define KC  32               // K-chunk = 1 MFMA k-step
#define NCH (CV / KC)        // 50 chunks
#define OG  4                // o's per block
#define NB  (OG * 32)        // 128 ncols

#define OUT_ELEMS ((size_t)N_ * O_ * T_ * V_)   // 13,107,200

typedef __attribute__((ext_vector_type(8))) short bf16x8;
typedef __attribute__((ext_vector_type(4))) float f32x4;

// round-to-nearest-away, 2 ops
static __device__ __forceinline__ unsigned short f2bf(float f) {
    union { float f; unsigned u; } c; c.f = f;
    return (unsigned short)((c.u + 0x8000u) >> 16);
}
static __device__ __forceinline__ float bf2f(unsigned short h) {
    union { unsigned u; float f; } c; c.u = ((unsigned)h) << 16; return c.f;
}
static __device__ __forceinline__ unsigned pk2(float a, float b) {
    union { float f; unsigned u; } ca, cb; ca.f = a; cb.f = b;
    return ((ca.u + 0x8000u) >> 16) | ((cb.u + 0x8000u) & 0xFFFF0000u);
}

// ---------------------------------------------------------------------------
// k_xcast: fragment-native xT3 with cv' = v*64+c ordering:
//   xT3[n][tt(16)][s'(200)][tl(16)][ke(8)],  s' = v*8 + c/8, ke = c&7.
// Also per-t-block partial pool sums pp[n][tb][c*25+v].
// ---------------------------------------------------------------------------
__global__ void k_xcast(const float* __restrict__ x, unsigned short* __restrict__ xT3,
                        float* __restrict__ pp) {
    __shared__ unsigned short tile[16][CV + 8];   // [t][c*25+v], row stride 3216 B
    int bid = blockIdx.x;
    int n = bid >> 4, tb = bid & 15;
    int tid = threadIdx.x;
    for (int i = tid; i < C_ * 16 * V_; i += 256) {
        int c = i / 400, r = i - c * 400;
        int t = r / 25, v = r - t * 25;
        float val = x[(((size_t)n * C_ + c) * T_ + tb * 16 + t) * V_ + v];
        tile[t][c * 25 + v] = f2bf(val);
    }
    __syncthreads();
    unsigned short* dstb = xT3 + ((size_t)(n * 16 + tb) * 200) * 128;
    for (int i = tid; i < 200 * 16; i += 256) {
        int sp = i >> 4, tl = i & 15;
        int v = sp >> 3, c0 = (sp & 7) * 8;
        unsigned short h[8];
#pragma unroll
        for (int j = 0; j < 8; ++j) h[j] = tile[tl][(c0 + j) * 25 + v];
        uint4 pk;
        pk.x = (unsigned)h[0] | ((unsigned)h[1] << 16);
        pk.y = (unsigned)h[2] | ((unsigned)h[3] << 16);
        pk.z = (unsigned)h[4] | ((unsigned)h[5] << 16);
        pk.w = (unsigned)h[6] | ((unsigned)h[7] << 16);
        *(uint4*)(dstb + (size_t)sp * 128 + tl * 8) = pk;
    }
    float* ppd = pp + ((size_t)n * 16 + tb) * CV;
    for (int e = tid; e < CV; e += 256) {
        float s = 0.f;
#pragma unroll
        for (int t = 0; t < 16; ++t) s += bf2f(tile[t][e]);
        ppd[e] = s;
    }
}

// pool[n][cv] = (1/T) * sum_tb pp[n][tb][cv]
__global__ void k_poolsum(const float* __restrict__ pp, float* __restrict__ pool) {
    int idx = blockIdx.x * 256 + threadIdx.x;
    int n = idx / CV, cv = idx - n * CV;
    float s = 0.f;
#pragma unroll
    for (int tb = 0; tb < 16; ++tb) s += pp[((size_t)n * 16 + tb) * CV + cv];
    pool[idx] = s * (1.0f / T_);
}

// classic pool (slow tier)
__global__ void k_pool(const float* __restrict__ x, float* __restrict__ pool) {
    int nc = blockIdx.x;
    int t  = threadIdx.x;
    const float* px = x + ((size_t)nc * T_ + t) * V_;
    float acc[V_];
#pragma unroll
    for (int v = 0; v < V_; ++v) acc[v] = px[v];
#pragma unroll
    for (int off = 32; off > 0; off >>= 1) {
#pragma unroll
        for (int v = 0; v < V_; ++v) acc[v] += __shfl_down(acc[v], off, 64);
    }
    __shared__ float sm[4][V_];
    int wave = t >> 6, lane = t & 63;
    if (lane == 0) {
#pragma unroll
        for (int v = 0; v < V_; ++v) sm[wave][v] = acc[v];
    }
    __syncthreads();
    if (t < V_) {
        float s = sm[0][t] + sm[1][t] + sm[2][t] + sm[3][t];
        pool[(size_t)nc * V_ + t] = s * (1.0f / T_);
    }
}

// ---------------------------------------------------------------------------
// k_tvals (slow tier only)
// ---------------------------------------------------------------------------
__global__ void k_tvals(const float* __restrict__ pool,
                        const float* __restrict__ W11, const float* __restrict__ b11,
                        const float* __restrict__ W12, const float* __restrict__ b12,
                        const float* __restrict__ W2,  const float* __restrict__ b2,
                        float* __restrict__ t2o, float* __restrict__ tSo) {
    int kn = blockIdx.x;
    int k = kn / N_, n = kn % N_;
    int tid = threadIdx.x;
    int r = tid >> 5, v = tid & 31;
    if (v >= V_) return;
    const float* pp = pool + (size_t)n * C_ * V_ + v;
    const float* w2 = W2 + ((size_t)k * R_ + r) * C_;
    const float* w1 = ((v < NU_) ? W11 : W12) + ((size_t)k * R_ + r) * C_;
    float a2 = b2[k * R_ + r];
    float a1 = (v < NU_) ? b11[k * R_ + r] : b12[k * R_ + r];
    for (int c = 0; c < C_; ++c) {
        float p = pp[(size_t)c * V_];
        a2 += w2[c] * p;
        a1 += w1[c] * p;
    }
    size_t idx = (((size_t)k * N_ + n) * R_ + r) * V_ + v;
    t2o[idx] = a2;
    tSo[idx] = a1;
}

// ---------------------------------------------------------------------------
// k_graphs (slow tier)
// ---------------------------------------------------------------------------
__global__ void k_graphs(const float* __restrict__ t2v, const float* __restrict__ tSv,
                         const float* __restrict__ W4, const float* __restrict__ b4,
                         float* __restrict__ graphs) {
    int kn = blockIdx.x;
    int k = kn / N_, n = kn % N_;
    int kup = (k + 1) % K_;
    __shared__ float F[R_][V_ * V_];
    __shared__ float w4s[O_][R_];
    __shared__ float b4s[O_];
    int tid = threadIdx.x;
    for (int i = tid; i < O_ * R_; i += 256) w4s[i / R_][i % R_] = W4[(size_t)k * O_ * R_ + i];
    if (tid < O_) b4s[tid] = b4[k * O_ + tid];
    for (int idx = tid; idx < R_ * V_ * V_; idx += 256) {
        int r = idx / (V_ * V_), uv = idx % (V_ * V_);
        int u = uv / V_, v = uv % V_;
        int ks = (u < NU_) ? kup : k;
        size_t base = (((size_t)ks * N_ + n) * R_ + r) * V_;
        F[r][uv] = tanhf(tSv[base + u] - t2v[base + v]);
    }
    __syncthreads();
    float* gout = graphs + ((size_t)k * N_ + n) * O_ * (V_ * V_);
    for (int idx = tid; idx < O_ * V_ * V_; idx += 256) {
        int o = idx / (V_ * V_), uv = idx % (V_ * V_);
        float a = b4s[o];
#pragma unroll
        for (int r = 0; r < R_; ++r) a += w4s[o][r] * F[r][uv];
        gout[idx] = a;
    }
}

// ---------------------------------------------------------------------------
// k_graphs2 (fast tier): fuses k_tvals — computes t2/tS for k AND kup in LDS.
// ---------------------------------------------------------------------------
__global__ void k_graphs2(const float* __restrict__ pool,
                          const float* __restrict__ W11, const float* __restrict__ b11,
                          const float* __restrict__ W12, const float* __restrict__ b12,
                          const float* __restrict__ W2,  const float* __restrict__ b2,
                          const float* __restrict__ W4,  const float* __restrict__ b4,
                          float* __restrict__ graphs) {
    int kn = blockIdx.x;
    int k = kn / N_, n = kn % N_;
    int kup = (k + 1) % K_;
    __shared__ float t2s[2][R_][V_];   // [0]=k, [1]=kup
    __shared__ float tSs[2][R_][V_];
    __shared__ float F[R_][V_ * V_];
    __shared__ float w4s[O_][R_];
    __shared__ float b4s[O_];
    int tid = threadIdx.x;
    for (int i = tid; i < O_ * R_; i += 256) w4s[i / R_][i % R_] = W4[(size_t)k * O_ * R_ + i];
    if (tid < O_) b4s[tid] = b4[k * O_ + tid];
    for (int i = tid; i < 2 * R_ * V_; i += 256) {
        int ks = i / (R_ * V_);
        int rem = i - ks * (R_ * V_);
        int r = rem / V_, v = rem - r * V_;
        int kk = ks ? kup : k;
        const float* pp = pool + (size_t)n * CV + v;
        const float* w2 = W2 + ((size_t)kk * R_ + r) * C_;
        const float* w1 = ((v < NU_) ? W11 : W12) + ((size_t)kk * R_ + r) * C_;
        float a2 = b2[kk * R_ + r];
        float a1 = (v < NU_) ? b11[kk * R_ + r] : b12[kk * R_ + r];
        for (int c = 0; c < C_; ++c) {
            float p = pp[(size_t)c * V_];
            a2 += w2[c] * p;
            a1 += w1[c] * p;
        }
        t2s[ks][r][v] = a2;
        tSs[ks][r][v] = a1;
    }
    __syncthreads();
    for (int idx = tid; idx < R_ * V_ * V_; idx += 256) {
        int r = idx / (V_ * V_), uv = idx % (V_ * V_);
        int u = uv / V_, v = uv % V_;
        int ks = (u < NU_) ? 1 : 0;
        F[r][uv] = tanhf(tSs[ks][r][u] - t2s[ks][r][v]);
    }
    __syncthreads();
    float* gout = graphs + ((size_t)k * N_ + n) * O_ * (V_ * V_);
    for (int idx = tid; idx < O_ * V_ * V_; idx += 256) {
        int o = idx / (V_ * V_), uv = idx % (V_ * V_);
        float a = b4s[o];
#pragma unroll
        for (int r = 0; r < R_; ++r) a += w4s[o][r] * F[r][uv];
        gout[idx] = a;
    }
}

// ---------------------------------------------------------------------------
// k_main_fast: per (n, 4-o group) GEMM  out[t,ncol] = bias + A·H over cv'=v*64+c
//   A = xT3 fragments (global, never LDS); H formed per chunk in LDS.
//   Chunk kc: v = kc>>1 (ONE v per chunk!), c = (kc&1)*32 + sl*8 + j.
//   Per thread: 1 G-load (f32x4+f32) amortized over 8 h-values; W3 k-major
//   -> 10 contiguous ds_read_b128 (wave-broadcast); 40 FMA; 2-op cvt.
// ---------------------------------------------------------------------------
__global__ __launch_bounds__(512, 4) void k_main_fast(
    const unsigned short* __restrict__ xT3,  // [N][16][200][16][8] bf16 bits
    const float* __restrict__ graphs,        // [K][N][O][625]
    const float* __restrict__ Adj,           // [K][625]
    const float* __restrict__ W3,            // [K][O][C]
    const float* __restrict__ b3,            // [K][O]
    float* __restrict__ out) {

    __shared__ unsigned short Hs[2][4][NB][8];   // 16 KB
    __shared__ f32x4 Gls4[OG * 625];             // 40 KB (k0..3), idx o*625+v*25+u
    __shared__ float Gls1[OG * 625];             // 10 KB (k4)
    __shared__ f32x4 W3km[K_ * OG * 16];         //  5 KB: [k][o][c], f32x4 over c
    __shared__ float biasS[NB];                  // 512 B

    const int tid = threadIdx.x;
    const int bid = blockIdx.x;
    const int obase = (bid & 15) * OG;
    const int n = bid >> 4;
    const int lane = tid & 63;
    const int wv_ = tid >> 6;

    // ---- stage Gls ----
    const size_t kstride = (size_t)N_ * O_ * 625;
    for (int i = tid; i < OG * 625; i += 512) {
        int o = i / 625, uv = i - o * 625;
        int u = uv / 25, v = uv - u * 25;
        size_t gb = ((size_t)n * O_ + obase + o) * 625 + uv;
        f32x4 g4;
        g4[0] = graphs[gb]               + Adj[uv];
        g4[1] = graphs[gb + kstride]     + Adj[625 + uv];
        g4[2] = graphs[gb + 2 * kstride] + Adj[1250 + uv];
        g4[3] = graphs[gb + 3 * kstride] + Adj[1875 + uv];
        int idx = o * 625 + v * 25 + u;
        Gls4[idx] = g4;
        Gls1[idx] = graphs[gb + 4 * kstride] + Adj[2500 + uv];
    }
    // ---- stage W3 k-major: W3km[(k*OG+o)*16 + c/4][c&3] ----
    for (int i = tid; i < K_ * OG * C_; i += 512) {   // 1280 scalars
        int k = i / (OG * C_);
        int rem = i - k * (OG * C_);
        int o = rem >> 6, c = rem & 63;
        ((float*)W3km)[((k * OG + o) * C_) + c] = W3[((size_t)k * O_ + obase + o) * C_ + c];
    }
    __syncthreads();

    // ---- in-block bias ----
    if (tid < NB) {
        int o = tid >> 5, u = tid & 31;
        float bv = 0.f;
        if (u < U_) {
            f32x4 s4 = {0.f, 0.f, 0.f, 0.f};
            float s5 = 0.f;
            for (int v = 0; v < V_; ++v) {
                int idx = o * 625 + v * 25 + u;
                s4 += Gls4[idx];
                s5 += Gls1[idx];
            }
            bv = s4[0] * b3[0 * O_ + obase + o] + s4[1] * b3[1 * O_ + obase + o]
               + s4[2] * b3[2 * O_ + obase + o] + s4[3] * b3[3 * O_ + obase + o]
               + s5 * b3[4 * O_ + obase + o];
        }
        biasS[tid] = bv;
    }

    // ---- H_FORM ----
    const int sl = wv_ & 3;
    const int hncol = (wv_ >> 2) * 64 + lane;   // 0..127
    const int ho = hncol >> 5;
    const int hu = hncol & 31;
    auto h_form = [&](int buf, int kc) {
        const int v  = kc >> 1;
        const int c0 = (kc & 1) * 32 + sl * 8;
        f32x4 g = {0.f, 0.f, 0.f, 0.f};
        float g5 = 0.f;
        if (hu < U_) {
            int gi = ho * 625 + v * 25 + hu;
            g = Gls4[gi];
            g5 = Gls1[gi];
        }
        const f32x4* wb = &W3km[(ho * 16) + (c0 >> 2)];
        const int kw = OG * 16;   // f32x4 stride per k
        f32x4 w0a = wb[0],        w0b = wb[1];
        f32x4 w1a = wb[kw],       w1b = wb[kw + 1];
        f32x4 w2a = wb[2 * kw],   w2b = wb[2 * kw + 1];
        f32x4 w3a = wb[3 * kw],   w3b = wb[3 * kw + 1];
        f32x4 w4a = wb[4 * kw],   w4b = wb[4 * kw + 1];
        float h[8];
#pragma unroll
        for (int j = 0; j < 4; ++j) {
            h[j]     = w0a[j] * g[0] + w1a[j] * g[1] + w2a[j] * g[2] + w3a[j] * g[3] + w4a[j] * g5;
            h[4 + j] = w0b[j] * g[0] + w1b[j] * g[1] + w2b[j] * g[2] + w3b[j] * g[3] + w4b[j] * g5;
        }
        uint4 hv;
        hv.x = pk2(h[0], h[1]); hv.y = pk2(h[2], h[3]);
        hv.z = pk2(h[4], h[5]); hv.w = pk2(h[6], h[7]);
        *(uint4*)&Hs[buf][sl][hncol][0] = hv;
    };

    // ---- MFMA wave grid ----
    const int wm = wv_ >> 1;            // 0..3 -> t-base wm*64
    const int wn = wv_ & 1;             // 0..1 -> ncol-base wn*64
    const int lr = lane & 15;
    const int eg = lane >> 4;

    f32x4 acc[4][4];
#pragma unroll
    for (int mt = 0; mt < 4; ++mt)
#pragma unroll
        for (int nt = 0; nt < 4; ++nt) acc[mt][nt] = (f32x4){0.f, 0.f, 0.f, 0.f};

    h_form(0, 0);
    __syncthreads();

    const unsigned short* An = xT3 + (size_t)n * (T_ * CV);

    for (int kc = 0; kc < NCH; ++kc) {
        const int cur = kc & 1;
        uint4 av[4];
#pragma unroll
        for (int mt = 0; mt < 4; ++mt) {
            int tt = wm * 4 + mt;
            av[mt] = *(const uint4*)(An + ((size_t)(tt * 200 + kc * 4 + eg)) * 128 + lr * 8);
        }
        bf16x8 b[4];
#pragma unroll
        for (int nt = 0; nt < 4; ++nt)
            b[nt] = *(const bf16x8*)&Hs[cur][eg][wn * 64 + nt * 16 + lr][0];
        __builtin_amdgcn_s_setprio(1);
#pragma unroll
        for (int mt = 0; mt < 4; ++mt) {
            bf16x8 a;
            { union { uint4 u; bf16x8 h; } cvt; cvt.u = av[mt]; a = cvt.h; }
#pragma unroll
            for (int nt = 0; nt < 4; ++nt)
                acc[mt][nt] = __builtin_amdgcn_mfma_f32_16x16x32_bf16(a, b[nt], acc[mt][nt], 0, 0, 0);
        }
        __builtin_amdgcn_s_setprio(0);
        if (kc + 1 < NCH) h_form(cur ^ 1, kc + 1);
        __syncthreads();
    }

    // ---- epilogue ----
#pragma unroll
    for (int nt = 0; nt < 4; ++nt) {
        int ncol = wn * 64 + nt * 16 + lr;
        int ol = ncol >> 5;
        int u  = ncol & 31;
        if (u < U_) {
            float bv = biasS[ncol];
            float* ob = out + ((size_t)n * O_ + obase + ol) * T_ * V_ + u;
#pragma unroll
            for (int mt = 0; mt < 4; ++mt) {
                int t0 = wm * 64 + mt * 16 + eg * 4;
#pragma unroll
                for (int r2 = 0; r2 < 4; ++r2)
                    ob[(size_t)(t0 + r2) * V_] = acc[mt][nt][r2] + bv;
            }
        }
    }
}

// ---------------------------------------------------------------------------
// k_main_slow (fallback, proven R2 path)
// ---------------------------------------------------------------------------
#define OB 4
#define TB 64
__global__ __launch_bounds__(256, 1) void k_main_slow(
    const float* __restrict__ x, const float* __restrict__ graphs,
    const float* __restrict__ A, const float* __restrict__ W3,
    const float* __restrict__ b3, float* __restrict__ out) {
    int bid = blockIdx.x;
    int tb = bid & 3;
    int ob = (bid >> 2) & 15;
    int n  = bid >> 6;
    int tid = threadIdx.x;
    int ol = tid >> 6;
    int tl = tid & 63;
    int t = tb * TB + tl;
    int o = ob * OB + ol;

    __shared__ float Gs[K_][OB][V_][28];
    __shared__ float W3s[K_][OB][C_];
    __shared__ float b3s[K_][OB];

    for (int i = tid; i < K_ * OB * V_ * V_; i += 256) {
        int k   = i / (OB * V_ * V_);
        int rem = i % (OB * V_ * V_);
        int oo  = rem / (V_ * V_);
        int uv  = rem % (V_ * V_);
        Gs[k][oo][uv / V_][uv % V_] =
            graphs[(((size_t)k * N_ + n) * O_ + ob * OB + oo) * (V_ * V_) + uv]
            + A[k * V_ * V_ + uv];
    }
    for (int i = tid; i < K_ * OB * C_; i += 256) {
        int k   = i / (OB * C_);
        int rem = i % (OB * C_);
        int oo  = rem / C_, c = rem % C_;
        W3s[k][oo][c] = W3[((size_t)k * O_ + ob * OB + oo) * C_ + c];
    }
    if (tid < K_ * OB) b3s[tid / OB][tid % OB] = b3[(tid / OB) * O_ + ob * OB + tid % OB];
    __syncthreads();

    float x2[K_][V_];
#pragma unroll
    for (int k = 0; k < K_; ++k)
#pragma unroll
        for (int v = 0; v < V_; ++v) x2[k][v] = b3s[k][ol];

    const float* xb = x + ((size_t)n * C_ * T_ + t) * V_;
    for (int c = 0; c < C_; ++c) {
        const float* p = xb + (size_t)c * T_ * V_;
        float xv[V_];
#pragma unroll
        for (int v = 0; v < V_; ++v) xv[v] = p[v];
#pragma unroll
        for (int k = 0; k < K_; ++k) {
            float w = W3s[k][ol][c];
#pragma unroll
            for (int v = 0; v < V_; ++v) x2[k][v] += w * xv[v];
        }
    }

    float acc[V_];
#pragma unroll
    for (int u = 0; u < V_; ++u) acc[u] = 0.0f;
#pragma unroll
    for (int k = 0; k < K_; ++k) {
#pragma unroll
        for (int u = 0; u < V_; ++u) {
            const float* gr = &Gs[k][ol][u][0];
            float s = 0.0f;
#pragma unroll
            for (int v = 0; v < V_; ++v) s += gr[v] * x2[k][v];
            acc[u] += s;
        }
    }
    float* po = out + (((size_t)n * O_ + o) * T_ + t) * V_;
#pragma unroll
    for (int u = 0; u < V_; ++u) po[u] = acc[u];
}

// ---------------------------------------------------------------------------
extern "C" void kernel_launch(void* const* d_in, const int* in_sizes, int n_in,
                              void* d_out, int out_size, void* d_ws, size_t ws_size,
                              hipStream_t stream) {
    const float* x   = (const float*)d_in[0];
    const float* A   = (const float*)d_in[1];
    const float* W11 = (const float*)d_in[2];
    const float* b11 = (const float*)d_in[3];
    const float* W12 = (const float*)d_in[4];
    const float* b12 = (const float*)d_in[5];
    const float* W2  = (const float*)d_in[6];
    const float* b2  = (const float*)d_in[7];
    const float* W3  = (const float*)d_in[8];
    const float* b3  = (const float*)d_in[9];
    const float* W4  = (const float*)d_in[10];
    const float* b4  = (const float*)d_in[11];

    float* out    = (float*)d_out;
    float* graphs = out + OUT_ELEMS;   // second tuple element

    const size_t xT_bytes = sizeof(unsigned short) * (size_t)N_ * T_ * CV;  // 26.2 MB
    const size_t pp_bytes = sizeof(float) * (size_t)N_ * 16 * CV;           //  3.3 MB
    const size_t hdr      = (size_t)(1 << 20);
    const bool fast = (ws_size >= hdr + xT_bytes + pp_bytes);

    const size_t poolElems = (size_t)N_ * C_ * V_;      // 51,200
    const size_t tElems    = (size_t)K_ * N_ * R_ * V_; // 32,000
    const size_t slowNeed  = (poolElems + 2 * tElems) * sizeof(float);

    float* scratch = (fast || ws_size >= slowNeed) ? (float*)d_ws : out;
    float* pool = scratch;
    float* t2v  = scratch + poolElems;
    float* tSv  = t2v + tElems;
    unsigned short* xT3 = (unsigned short*)((char*)d_ws + hdr);
    float* pp = (float*)((char*)d_ws + hdr + xT_bytes);

    if (fast) {
        k_xcast  <<<N_ * 16, 256, 0, stream>>>(x, xT3, pp);
        k_poolsum<<<(N_ * CV) / 256, 256, 0, stream>>>(pp, pool);
        k_graphs2<<<K_ * N_, 256, 0, stream>>>(pool, W11, b11, W12, b12, W2, b2, W4, b4, graphs);
        k_main_fast<<<N_ * 16, 512, 0, stream>>>(xT3, graphs, A, W3, b3, out);
    } else {
        k_pool  <<<N_ * C_, 256, 0, stream>>>(x, pool);
        k_tvals <<<K_ * N_, 256, 0, stream>>>(pool, W11, b11, W12, b12, W2, b2, t2v, tSv);
        k_graphs<<<K_ * N_, 256, 0, stream>>>(t2v, tSv, W4, b4, graphs);
        k_main_slow<<<N_ * (O_ / OB) * 4, 256, 0, stream>>>(x, graphs, A, W3, b3, out);
    }
}